// Round 1
// baseline (735.921 us; speedup 1.0000x reference)
//
#include <hip/hip_runtime.h>

typedef _Float16 f16x8 __attribute__((ext_vector_type(8)));
typedef float f32x4 __attribute__((ext_vector_type(4)));

// ---------------------------------------------------------------------------
// K1: per (bf quadrant, wc row of 24 centers):
//   xc = 2x2-avgpool(x);  centers = W_f xc + b_f; vc = W_v xc + b_v
//   cen = centers/||centers||;  cenW[m][cin] = W_f^T cen[m] (f16 hi/lo split)
//   d[m] = cen[m]·b_f;  pooled := vc;  counts := 1
//   side jobs: w_v -> f16, w_skip -> f16 reordered [co][dh*3+dw][cin], gn zero
// ---------------------------------------------------------------------------
__global__ __launch_bounds__(256) void k1_centers(
    const float* __restrict__ x, const float* __restrict__ w_f,
    const float* __restrict__ b_f, const float* __restrict__ w_v,
    const float* __restrict__ b_v, const float* __restrict__ w_skip,
    _Float16* __restrict__ cenW_h, _Float16* __restrict__ cenW_l,
    float* __restrict__ dvec, float* __restrict__ pooled,
    float* __restrict__ counts, _Float16* __restrict__ w_v_h,
    _Float16* __restrict__ w_skip_h, float* __restrict__ gn_sum,
    float* __restrict__ gn_ss)
{
  const int wc = blockIdx.x;          // 0..23
  const int bf = blockIdx.y;          // 0..63
  const int b = bf >> 2, f1 = (bf >> 1) & 1, f2 = bf & 1;
  const int t = threadIdx.x;

  __shared__ float wf[128][65];       // pad 65: 2-way max on strided reads
  __shared__ float wv[128][65];
  __shared__ float xc[24][64];
  __shared__ float cent[24][130];
  __shared__ float inv_l[24];

  for (int i = t; i < 128 * 64; i += 256) {
    int co = i >> 6, c = i & 63;
    wf[co][c] = w_f[i];
    wv[co][c] = w_v[i];
  }
  for (int e = t; e < 64 * 24; e += 256) {
    int c = e / 24, hc = e % 24;
    const float* xp = x + ((size_t)(b * 64 + c) * 96 + (f1 * 48 + 2 * wc)) * 96
                        + f2 * 48 + 2 * hc;
    xc[hc][c] = 0.25f * (xp[0] + xp[1] + xp[96] + xp[97]);
  }
  __syncthreads();
  {
    const int co = t & 127;
    const int hg = t >> 7;
    for (int p = 0; p < 12; ++p) {
      int hc = p * 2 + hg;
      float accf = b_f[co], accv = b_v[co];
      #pragma unroll
      for (int c = 0; c < 64; ++c) {
        float xv = xc[hc][c];
        accf = fmaf(wf[co][c], xv, accf);
        accv = fmaf(wv[co][c], xv, accv);
      }
      cent[hc][co] = accf;
      pooled[((size_t)bf * 576 + wc * 24 + hc) * 128 + co] = accv;
    }
  }
  __syncthreads();
  if (t < 24) {
    float ss = 0.f, db = 0.f;
    for (int c = 0; c < 128; ++c) { float v = cent[t][c]; ss += v * v; db += v * b_f[c]; }
    float inv = 1.0f / fmaxf(sqrtf(ss), 1e-12f);
    inv_l[t] = inv;
    dvec[bf * 576 + wc * 24 + t] = inv * db;
    counts[bf * 576 + wc * 24 + t] = 1.0f;
  }
  __syncthreads();
  for (int e = t; e < 24 * 64; e += 256) {
    int hc = e >> 6, c = e & 63;
    float acc = 0.f;
    for (int co2 = 0; co2 < 128; ++co2) acc = fmaf(cent[hc][co2], wf[co2][c], acc);
    acc *= inv_l[hc];
    _Float16 hi = (_Float16)acc;
    size_t o = ((size_t)bf * 576 + wc * 24 + hc) * 64 + c;
    cenW_h[o] = hi;
    cenW_l[o] = (_Float16)(acc - (float)hi);
  }
  if (bf == 0 && wc == 0) {
    for (int i = t; i < 128 * 64; i += 256) w_v_h[i] = (_Float16)w_v[i];
    if (t < 16) { gn_sum[t] = 0.f; gn_ss[t] = 0.f; }
  }
  if (bf == 1) {
    // w_skip_h[co][dd][c] <- w_skip[co][c][dh][dw]; 73728 elems over 24 blocks
    for (int i = wc * 3072 + t; i < wc * 3072 + 3072; i += 256) {
      int co = i / 576, r = i % 576, dd = r >> 6, c = r & 63;
      w_skip_h[i] = (_Float16)w_skip[((co * 64 + c) * 3 + dd / 3) * 3 + (dd % 3)];
    }
  }
}

// ---------------------------------------------------------------------------
// K2: per (bf, tile of 144 points = 3 rows of 48):
//   stage x as f16 hi/lo in LDS [n][c];
//   argmax_m ( cenW[m]·x[n] + d[m] ) via 3-term split f16 MFMA (16x16x32);
//   value[co][n] = W_vh·xh + b_v via 1-pass f16 MFMA; atomic scatter to pooled.
// ---------------------------------------------------------------------------
__global__ __launch_bounds__(256) void k2_assign(
    const float* __restrict__ x,
    const _Float16* __restrict__ cenW_h, const _Float16* __restrict__ cenW_l,
    const float* __restrict__ dvec, const _Float16* __restrict__ w_v_h,
    const float* __restrict__ b_v,
    float* __restrict__ pooled, float* __restrict__ counts)
{
  const int tile = blockIdx.x;        // 0..15
  const int bf = blockIdx.y;          // 0..63
  const int b = bf >> 2, f1 = (bf >> 1) & 1, f2 = bf & 1;
  const int t = threadIdx.x;
  const int lane = t & 63, wid = t >> 6;

  __shared__ __align__(16) _Float16 xh[144][72];  // stride 72: 16B-aligned rows, 2-way banks
  __shared__ __align__(16) _Float16 xl[144][72];
  __shared__ float wbv[4][144];
  __shared__ int   wbi[4][144];
  __shared__ int   idxf[144];

  const int w0 = tile * 3;
  for (int i = t; i < 64 * 144; i += 256) {
    int c = i / 144, j = i % 144;
    int wl = j / 48, h = j % 48;
    float v = x[((size_t)(b * 64 + c) * 96 + (f1 * 48 + w0 + wl)) * 96 + f2 * 48 + h];
    _Float16 hi = (_Float16)v;
    xh[j][c] = hi;
    xl[j][c] = (_Float16)(v - (float)hi);
  }
  __syncthreads();

  float bestv[9];
  int   besti[9];
  #pragma unroll
  for (int nb = 0; nb < 9; ++nb) { bestv[nb] = -3.0e38f; besti[nb] = 0; }

  const int ccol = lane & 15;           // A row / B col / C col
  const int row0 = (lane >> 4) * 4;     // C row base
  const int c0   = (lane >> 4) * 8;     // A/B k base

  for (int mb = wid; mb < 36; mb += 4) {
    const size_t abase = ((size_t)bf * 576 + mb * 16 + ccol) * 64;
    f16x8 ah0 = *(const f16x8*)(cenW_h + abase + c0);
    f16x8 ah1 = *(const f16x8*)(cenW_h + abase + 32 + c0);
    f16x8 al0 = *(const f16x8*)(cenW_l + abase + c0);
    f16x8 al1 = *(const f16x8*)(cenW_l + abase + 32 + c0);
    float dv[4];
    #pragma unroll
    for (int r = 0; r < 4; ++r) dv[r] = dvec[bf * 576 + mb * 16 + row0 + r];
    #pragma unroll 3
    for (int nb = 0; nb < 9; ++nb) {
      int n = nb * 16 + ccol;
      f16x8 bh0 = *(const f16x8*)(&xh[n][c0]);
      f16x8 bh1 = *(const f16x8*)(&xh[n][32 + c0]);
      f16x8 bl0 = *(const f16x8*)(&xl[n][c0]);
      f16x8 bl1 = *(const f16x8*)(&xl[n][32 + c0]);
      f32x4 acc = {0.f, 0.f, 0.f, 0.f};
      acc = __builtin_amdgcn_mfma_f32_16x16x32_f16(ah0, bh0, acc, 0, 0, 0);
      acc = __builtin_amdgcn_mfma_f32_16x16x32_f16(ah1, bh1, acc, 0, 0, 0);
      acc = __builtin_amdgcn_mfma_f32_16x16x32_f16(ah0, bl0, acc, 0, 0, 0);
      acc = __builtin_amdgcn_mfma_f32_16x16x32_f16(ah1, bl1, acc, 0, 0, 0);
      acc = __builtin_amdgcn_mfma_f32_16x16x32_f16(al0, bh0, acc, 0, 0, 0);
      acc = __builtin_amdgcn_mfma_f32_16x16x32_f16(al1, bh1, acc, 0, 0, 0);
      #pragma unroll
      for (int r = 0; r < 4; ++r) {
        float v = acc[r] + dv[r];
        int m = mb * 16 + row0 + r;
        if (v > bestv[nb] || (v == bestv[nb] && m < besti[nb])) { bestv[nb] = v; besti[nb] = m; }
      }
    }
  }

  #pragma unroll
  for (int nb = 0; nb < 9; ++nb) {
    float v = bestv[nb]; int mi = besti[nb];
    #pragma unroll
    for (int off = 16; off <= 32; off <<= 1) {
      float ov = __shfl_xor(v, off, 64);
      int   oi = __shfl_xor(mi, off, 64);
      if (ov > v || (ov == v && oi < mi)) { v = ov; mi = oi; }
    }
    if (lane < 16) { wbv[wid][nb * 16 + lane] = v; wbi[wid][nb * 16 + lane] = mi; }
  }
  __syncthreads();
  if (t < 144) {
    float v = wbv[0][t]; int mi = wbi[0][t];
    for (int w2 = 1; w2 < 4; ++w2) {
      float ov = wbv[w2][t]; int oi = wbi[w2][t];
      if (ov > v || (ov == v && oi < mi)) { v = ov; mi = oi; }
    }
    idxf[t] = mi;
    atomicAdd(counts + bf * 576 + mi, 1.0f);
  }
  __syncthreads();

  // value + scatter (1-pass f16: error ~7e-4 << 0.159 threshold)
  for (int mb2 = wid * 2; mb2 < wid * 2 + 2; ++mb2) {
    const size_t wbase = (size_t)(mb2 * 16 + ccol) * 64;
    f16x8 a0 = *(const f16x8*)(w_v_h + wbase + c0);
    f16x8 a1 = *(const f16x8*)(w_v_h + wbase + 32 + c0);
    float bv[4];
    #pragma unroll
    for (int r = 0; r < 4; ++r) bv[r] = b_v[mb2 * 16 + row0 + r];
    #pragma unroll 3
    for (int nb = 0; nb < 9; ++nb) {
      int n = nb * 16 + ccol;
      f16x8 bh0 = *(const f16x8*)(&xh[n][c0]);
      f16x8 bh1 = *(const f16x8*)(&xh[n][32 + c0]);
      f32x4 acc = {0.f, 0.f, 0.f, 0.f};
      acc = __builtin_amdgcn_mfma_f32_16x16x32_f16(a0, bh0, acc, 0, 0, 0);
      acc = __builtin_amdgcn_mfma_f32_16x16x32_f16(a1, bh1, acc, 0, 0, 0);
      int mi = idxf[n];
      float* pb = pooled + ((size_t)bf * 576 + mi) * 128 + mb2 * 16 + row0;
      #pragma unroll
      for (int r = 0; r < 4; ++r) atomicAdd(pb + r, acc[r] + bv[r]);
    }
  }
}

// ---------------------------------------------------------------------------
// K3: GroupNorm stats: sum / sumsq of pooled/counts per batch b (4 bf each)
// ---------------------------------------------------------------------------
__global__ __launch_bounds__(256) void k3_stats(
    const float* __restrict__ pooled, const float* __restrict__ counts,
    float* __restrict__ gn_sum, float* __restrict__ gn_ss)
{
  const int chunk = blockIdx.x;       // 0..3
  const int bf = blockIdx.y;          // 0..63
  const int t = threadIdx.x;
  float s = 0.f, ss = 0.f;
  for (int i = chunk * 18432 + t; i < chunk * 18432 + 18432; i += 256) {
    int m = i >> 7;
    float v = pooled[(size_t)bf * 73728 + i] / counts[bf * 576 + m];
    s += v; ss += v * v;
  }
  #pragma unroll
  for (int off = 1; off < 64; off <<= 1) {
    s += __shfl_xor(s, off, 64);
    ss += __shfl_xor(ss, off, 64);
  }
  __shared__ float rs[4], rss[4];
  const int lane = t & 63, wid = t >> 6;
  if (lane == 0) { rs[wid] = s; rss[wid] = ss; }
  __syncthreads();
  if (t == 0) {
    atomicAdd(gn_sum + (bf >> 2), rs[0] + rs[1] + rs[2] + rs[3]);
    atomicAdd(gn_ss + (bf >> 2), rss[0] + rss[1] + rss[2] + rss[3]);
  }
}

// ---------------------------------------------------------------------------
// K4: per (b, output row o2): skip conv via implicit-GEMM f16 MFMA (K=576)
//     + GroupNorm apply + unfold + add.  xcol parity-split for 2-way banks.
// ---------------------------------------------------------------------------
__global__ __launch_bounds__(256) void k4_final(
    const float* __restrict__ x, const _Float16* __restrict__ w_skip_h,
    const float* __restrict__ b_skip, const float* __restrict__ pooled,
    const float* __restrict__ counts, const float* __restrict__ gn_sum,
    const float* __restrict__ gn_ss, const float* __restrict__ gamma,
    const float* __restrict__ beta, float* __restrict__ out)
{
  const int o2 = blockIdx.x;          // 0..47
  const int b = blockIdx.y;           // 0..15
  const int t = threadIdx.x;
  const int lane = t & 63, wid = t >> 6;

  __shared__ __align__(16) _Float16 xcol[3][2][49][72]; // [dh][cc&1][cc>>1][c]
  __shared__ _Float16 raw[64][3][98];

  for (int i = t; i < 64 * 3 * 96; i += 256) {
    int c = i / 288, r = i % 288, dh = r / 96, col = r % 96;
    int R = 2 * o2 + dh - 1;
    float v = (R >= 0) ? x[((size_t)(b * 64 + c) * 96 + R) * 96 + col] : 0.f;
    raw[c][dh][col] = (_Float16)v;
  }
  __syncthreads();
  for (int i = t; i < 3 * 98 * 64; i += 256) {
    int c = i & 63, r = i >> 6, cc = r % 98, dh = r / 98;
    _Float16 v = (_Float16)0.f;
    if (cc >= 1 && cc <= 96) v = raw[c][dh][cc - 1];
    xcol[dh][cc & 1][cc >> 1][c] = v;
  }
  __syncthreads();

  const float Ninv = 1.0f / 294912.0f;
  const float mu = gn_sum[b] * Ninv;
  const float var = gn_ss[b] * Ninv - mu * mu;
  const float istd = rsqrtf(var + 1e-5f);
  const int f1 = o2 / 24, w24 = o2 % 24;

  const int ccol = lane & 15, row0 = (lane >> 4) * 4, c0 = (lane >> 4) * 8;

  for (int tt = wid * 6; tt < wid * 6 + 6; ++tt) {
    int mb = tt / 3, nb = tt % 3;
    f32x4 acc = {0.f, 0.f, 0.f, 0.f};
    const _Float16* wrow = w_skip_h + (size_t)(mb * 16 + ccol) * 576;
    const int o3 = nb * 16 + ccol;
    #pragma unroll
    for (int ks = 0; ks < 18; ++ks) {
      int dd = ks >> 1;
      int dh = dd / 3, dw = dd % 3;
      int cl = (ks & 1) * 32 + c0;
      f16x8 a = *(const f16x8*)(wrow + ks * 32 + c0);
      f16x8 bb = *(const f16x8*)(&xcol[dh][dw & 1][o3 + (dw >> 1)][cl]);
      acc = __builtin_amdgcn_mfma_f32_16x16x32_f16(a, bb, acc, 0, 0, 0);
    }
    const int f2 = o3 / 24, h = o3 % 24;
    const int bf = ((b * 2 + f1) * 2) + f2;
    const int m = w24 * 24 + h;
    const float cinv = 1.0f / counts[bf * 576 + m];
    #pragma unroll
    for (int r = 0; r < 4; ++r) {
      int co = mb * 16 + row0 + r;
      float om = pooled[((size_t)bf * 576 + m) * 128 + co] * cinv;
      float gnv = (om - mu) * istd * gamma[co] + beta[co];
      out[((size_t)(b * 128 + co) * 48 + o2) * 48 + o3] = acc[r] + b_skip[co] + gnv;
    }
  }
}

// ---------------------------------------------------------------------------
extern "C" void kernel_launch(void* const* d_in, const int* in_sizes, int n_in,
                              void* d_out, int out_size, void* d_ws, size_t ws_size,
                              hipStream_t stream) {
  const float* x      = (const float*)d_in[0];
  const float* w_f    = (const float*)d_in[1];
  const float* b_f    = (const float*)d_in[2];
  const float* w_v    = (const float*)d_in[3];
  const float* b_v    = (const float*)d_in[4];
  const float* w_skip = (const float*)d_in[5];
  const float* b_skip = (const float*)d_in[6];
  const float* gamma  = (const float*)d_in[7];
  const float* beta   = (const float*)d_in[8];
  float* out = (float*)d_out;

  char* ws = (char*)d_ws;
  _Float16* cenW_h   = (_Float16*)(ws);
  _Float16* cenW_l   = (_Float16*)(ws + 4718592);
  float*    dvec     = (float*)(ws + 9437184);
  float*    pooled   = (float*)(ws + 9584640);
  float*    counts   = (float*)(ws + 28459008);
  _Float16* w_v_h    = (_Float16*)(ws + 28606464);
  _Float16* w_skip_h = (_Float16*)(ws + 28622848);
  float*    gn_sum   = (float*)(ws + 28770304);
  float*    gn_ss    = (float*)(ws + 28770368);

  k1_centers<<<dim3(24, 64), dim3(256), 0, stream>>>(
      x, w_f, b_f, w_v, b_v, w_skip, cenW_h, cenW_l, dvec, pooled, counts,
      w_v_h, w_skip_h, gn_sum, gn_ss);
  k2_assign<<<dim3(16, 64), dim3(256), 0, stream>>>(
      x, cenW_h, cenW_l, dvec, w_v_h, b_v, pooled, counts);
  k3_stats<<<dim3(4, 64), dim3(256), 0, stream>>>(pooled, counts, gn_sum, gn_ss);
  k4_final<<<dim3(48, 16), dim3(256), 0, stream>>>(
      x, w_skip_h, b_skip, pooled, counts, gn_sum, gn_ss, gamma, beta, out);
}

// Round 2
// 406.795 us; speedup vs baseline: 1.8091x; 1.8091x over previous
//
#include <hip/hip_runtime.h>

typedef _Float16 f16x8 __attribute__((ext_vector_type(8)));
typedef _Float16 f16x4 __attribute__((ext_vector_type(4)));
typedef float f32x4 __attribute__((ext_vector_type(4)));

// ---------------------------------------------------------------------------
// K1: per (bf quadrant, wc row of 24 centers):
//   xc = 2x2-avgpool(x)  (stored for K2c);  centers = W_f xc + b_f
//   cen = centers/||centers||;  cenW[m][cin] = W_f^T cen[m] (f16 hi/lo split)
//   d[m] = cen[m]·b_f
//   side jobs: w_v -> f16, w_skip -> f16 reordered [co][dh*3+dw][cin]
// ---------------------------------------------------------------------------
__global__ __launch_bounds__(256) void k1_centers(
    const float* __restrict__ x, const float* __restrict__ w_f,
    const float* __restrict__ b_f, const float* __restrict__ w_v,
    const float* __restrict__ w_skip,
    _Float16* __restrict__ cenW_h, _Float16* __restrict__ cenW_l,
    float* __restrict__ dvec, float* __restrict__ xc_buf,
    _Float16* __restrict__ w_v_h, _Float16* __restrict__ w_skip_h)
{
  const int wc = blockIdx.x;          // 0..23
  const int bf = blockIdx.y;          // 0..63
  const int b = bf >> 2, f1 = (bf >> 1) & 1, f2 = bf & 1;
  const int t = threadIdx.x;

  __shared__ float wf[128][65];
  __shared__ float xc[24][64];
  __shared__ float cent[24][130];
  __shared__ float inv_l[24];

  for (int i = t; i < 128 * 64; i += 256) {
    int co = i >> 6, c = i & 63;
    wf[co][c] = w_f[i];
  }
  for (int e = t; e < 64 * 24; e += 256) {
    int c = e / 24, hc = e % 24;
    const float* xp = x + ((size_t)(b * 64 + c) * 96 + (f1 * 48 + 2 * wc)) * 96
                        + f2 * 48 + 2 * hc;
    xc[hc][c] = 0.25f * (xp[0] + xp[1] + xp[96] + xp[97]);
  }
  __syncthreads();
  {
    const int co = t & 127;
    const int hg = t >> 7;
    for (int p = 0; p < 12; ++p) {
      int hc = p * 2 + hg;
      float accf = b_f[co];
      #pragma unroll
      for (int c = 0; c < 64; ++c) accf = fmaf(wf[co][c], xc[hc][c], accf);
      cent[hc][co] = accf;
    }
  }
  for (int e = t; e < 24 * 64; e += 256) {
    int hc = e >> 6, c = e & 63;
    xc_buf[((size_t)bf * 576 + wc * 24 + hc) * 64 + c] = xc[hc][c];
  }
  __syncthreads();
  if (t < 24) {
    float ss = 0.f, db = 0.f;
    for (int c = 0; c < 128; ++c) { float v = cent[t][c]; ss += v * v; db += v * b_f[c]; }
    float inv = 1.0f / fmaxf(sqrtf(ss), 1e-12f);
    inv_l[t] = inv;
    dvec[bf * 576 + wc * 24 + t] = inv * db;
  }
  __syncthreads();
  for (int e = t; e < 24 * 64; e += 256) {
    int hc = e >> 6, c = e & 63;
    float acc = 0.f;
    for (int co2 = 0; co2 < 128; ++co2) acc = fmaf(cent[hc][co2], wf[co2][c], acc);
    acc *= inv_l[hc];
    _Float16 hi = (_Float16)acc;
    size_t o = ((size_t)bf * 576 + wc * 24 + hc) * 64 + c;
    cenW_h[o] = hi;
    cenW_l[o] = (_Float16)(acc - (float)hi);
  }
  if (bf == 0 && wc == 0) {
    for (int i = t; i < 128 * 64; i += 256) w_v_h[i] = (_Float16)w_v[i];
  }
  if (bf == 1) {
    for (int i = wc * 3072 + t; i < wc * 3072 + 3072; i += 256) {
      int co = i / 576, r = i % 576, dd = r >> 6, c = r & 63;
      w_skip_h[i] = (_Float16)w_skip[((co * 64 + c) * 3 + dd / 3) * 3 + (dd % 3)];
    }
  }
}

// ---------------------------------------------------------------------------
// K2: per (bf, tile of 128 points = 8 rows x 16 cols):
//   argmax_m ( cenW[m]·x[n] + d[m] ) via 3-term split f16 MFMA;
//   segment-sum x (64 ch) into LDS 6x10 local-center window (outliers ->
//   direct global atomic), then one dense global atomic row per used center.
//   1-D grid swizzled so all 18 tiles of a bf share one XCD (L2-local atomics).
// ---------------------------------------------------------------------------
__global__ __launch_bounds__(256) void k2_assign(
    const float* __restrict__ x,
    const _Float16* __restrict__ cenW_h, const _Float16* __restrict__ cenW_l,
    const float* __restrict__ dvec,
    float* __restrict__ xsum, float* __restrict__ counts)
{
  const int id = blockIdx.x;          // 0..1151
  const int xcd = id & 7;
  const int j = id >> 3;              // 0..143
  const int bf = xcd * 8 + j / 18;
  const int tile = j % 18;
  const int b = bf >> 2, f1 = (bf >> 1) & 1, f2 = bf & 1;
  const int t = threadIdx.x;
  const int lane = t & 63, wid = t >> 6;

  const int tr = tile / 3, tc = tile % 3;
  const int w0 = tr * 8, h0 = tc * 16;
  const int mr0 = tr * 4 - 1, mc0 = tc * 8 - 1;   // 6x10 center window

  __shared__ __align__(16) _Float16 xh[128][72];
  __shared__ __align__(16) _Float16 xl[128][72];
  __shared__ float wbv[4][128];
  __shared__ int   wbi[4][128];
  __shared__ int   idxf[128];
  __shared__ int   spl[128];
  __shared__ int   mult[64];
  __shared__ float acc[60][64];

  for (int i = t; i < 60 * 64; i += 256) ((float*)acc)[i] = 0.f;
  if (t < 64) mult[t] = 0;

  for (int i = t; i < 64 * 128; i += 256) {
    int c = i >> 7, jj = i & 127;
    int wl = jj >> 4, hc = jj & 15;
    float v = x[((size_t)(b * 64 + c) * 96 + (f1 * 48 + w0 + wl)) * 96
                + f2 * 48 + h0 + hc];
    _Float16 hi = (_Float16)v;
    xh[jj][c] = hi;
    xl[jj][c] = (_Float16)(v - (float)hi);
  }
  __syncthreads();

  float bestv[8];
  int   besti[8];
  #pragma unroll
  for (int nb = 0; nb < 8; ++nb) { bestv[nb] = -3.0e38f; besti[nb] = 0; }

  const int ccol = lane & 15;
  const int row0 = (lane >> 4) * 4;
  const int c0   = (lane >> 4) * 8;

  for (int mb = wid; mb < 36; mb += 4) {
    const size_t abase = ((size_t)bf * 576 + mb * 16 + ccol) * 64;
    f16x8 ah0 = *(const f16x8*)(cenW_h + abase + c0);
    f16x8 ah1 = *(const f16x8*)(cenW_h + abase + 32 + c0);
    f16x8 al0 = *(const f16x8*)(cenW_l + abase + c0);
    f16x8 al1 = *(const f16x8*)(cenW_l + abase + 32 + c0);
    float dv[4];
    #pragma unroll
    for (int r = 0; r < 4; ++r) dv[r] = dvec[bf * 576 + mb * 16 + row0 + r];
    #pragma unroll 2
    for (int nb = 0; nb < 8; ++nb) {
      int n = nb * 16 + ccol;
      f16x8 bh0 = *(const f16x8*)(&xh[n][c0]);
      f16x8 bh1 = *(const f16x8*)(&xh[n][32 + c0]);
      f16x8 bl0 = *(const f16x8*)(&xl[n][c0]);
      f16x8 bl1 = *(const f16x8*)(&xl[n][32 + c0]);
      f32x4 a2 = {0.f, 0.f, 0.f, 0.f};
      a2 = __builtin_amdgcn_mfma_f32_16x16x32_f16(ah0, bh0, a2, 0, 0, 0);
      a2 = __builtin_amdgcn_mfma_f32_16x16x32_f16(ah1, bh1, a2, 0, 0, 0);
      a2 = __builtin_amdgcn_mfma_f32_16x16x32_f16(ah0, bl0, a2, 0, 0, 0);
      a2 = __builtin_amdgcn_mfma_f32_16x16x32_f16(ah1, bl1, a2, 0, 0, 0);
      a2 = __builtin_amdgcn_mfma_f32_16x16x32_f16(al0, bh0, a2, 0, 0, 0);
      a2 = __builtin_amdgcn_mfma_f32_16x16x32_f16(al1, bh1, a2, 0, 0, 0);
      #pragma unroll
      for (int r = 0; r < 4; ++r) {
        float v = a2[r] + dv[r];
        int m = mb * 16 + row0 + r;
        if (v > bestv[nb] || (v == bestv[nb] && m < besti[nb])) { bestv[nb] = v; besti[nb] = m; }
      }
    }
  }

  #pragma unroll
  for (int nb = 0; nb < 8; ++nb) {
    float v = bestv[nb]; int mi = besti[nb];
    #pragma unroll
    for (int off = 16; off <= 32; off <<= 1) {
      float ov = __shfl_xor(v, off, 64);
      int   oi = __shfl_xor(mi, off, 64);
      if (ov > v || (ov == v && oi < mi)) { v = ov; mi = oi; }
    }
    if (lane < 16) { wbv[wid][nb * 16 + lane] = v; wbi[wid][nb * 16 + lane] = mi; }
  }
  __syncthreads();
  if (t < 128) {
    float v = wbv[0][t]; int mi = wbi[0][t];
    for (int w2 = 1; w2 < 4; ++w2) {
      float ov = wbv[w2][t]; int oi = wbi[w2][t];
      if (ov > v || (ov == v && oi < mi)) { v = ov; mi = oi; }
    }
    idxf[t] = mi;
    int mr = mi / 24, mc = mi % 24;
    int dr = mr - mr0, dc = mc - mc0;
    if (dr >= 0 && dr < 6 && dc >= 0 && dc < 10) {
      int s = dr * 10 + dc;
      spl[t] = s;
      atomicAdd(&mult[s], 1);
    } else {
      spl[t] = -1;
      atomicAdd(&counts[bf * 576 + mi], 1.0f);
    }
  }
  __syncthreads();

  // segment-sum x into LDS window (wave = one point, lanes = 64 channels)
  for (int base = 0; base < 128; base += 4) {
    int p = base + wid;
    float v = (float)xh[p][lane] + (float)xl[p][lane];
    int s = spl[p];
    if (s >= 0) atomicAdd(&acc[s][lane], v);
    else atomicAdd(&xsum[((size_t)bf * 576 + idxf[p]) * 64 + lane], v);
  }
  __syncthreads();

  for (int base = 0; base < 60; base += 4) {
    int u = base + wid;
    if (u < 60 && mult[u] > 0) {
      int m = (mr0 + u / 10) * 24 + (mc0 + u % 10);
      atomicAdd(&xsum[((size_t)bf * 576 + m) * 64 + lane], acc[u][lane]);
      if (lane == 0) atomicAdd(&counts[bf * 576 + m], (float)mult[u]);
    }
  }
}

// ---------------------------------------------------------------------------
// K2c: pooled GEMM + divide + GroupNorm stats (replaces value GEMM + K3):
//   om[m][co] = (W_v·(xsum[m]+xc[m]))/(cnt[m]+1) + b_v[co]   (f16 out)
//   gn_sum/gn_ss += per-b partial sums of om.
// ---------------------------------------------------------------------------
__global__ __launch_bounds__(256) void k2c_pool(
    const float* __restrict__ xsum, const float* __restrict__ xc,
    const float* __restrict__ counts, const _Float16* __restrict__ w_v_h,
    const float* __restrict__ b_v, _Float16* __restrict__ om,
    float* __restrict__ gn_sum, float* __restrict__ gn_ss)
{
  const int chunk = blockIdx.x;       // 0..3
  const int bf = blockIdx.y;          // 0..63
  const int m0 = chunk * 144;
  const int t = threadIdx.x;
  const int lane = t & 63, wid = t >> 6;

  __shared__ __align__(16) _Float16 bh[144][72];
  __shared__ __align__(16) _Float16 bl[144][72];
  __shared__ float rcp_l[144];

  for (int i = t; i < 144 * 64; i += 256) {
    int mq = i >> 6, c = i & 63;
    size_t g = ((size_t)bf * 576 + m0 + mq) * 64 + c;
    float s = xsum[g] + xc[g];
    _Float16 hi = (_Float16)s;
    bh[mq][c] = hi;
    bl[mq][c] = (_Float16)(s - (float)hi);
  }
  if (t < 144) rcp_l[t] = 1.0f / (counts[bf * 576 + m0 + t] + 1.0f);
  __syncthreads();

  const int ccol = lane & 15, row0 = (lane >> 4) * 4, c0 = (lane >> 4) * 8;
  float sacc = 0.f, ssacc = 0.f;

  #pragma unroll
  for (int cbi = 0; cbi < 2; ++cbi) {
    const int cb = wid + cbi * 4;
    const size_t abase = (size_t)(cb * 16 + ccol) * 64;
    f16x8 a0 = *(const f16x8*)(w_v_h + abase + c0);
    f16x8 a1 = *(const f16x8*)(w_v_h + abase + 32 + c0);
    float bvv[4];
    #pragma unroll
    for (int r = 0; r < 4; ++r) bvv[r] = b_v[cb * 16 + row0 + r];
    for (int nb = 0; nb < 9; ++nb) {
      int mq = nb * 16 + ccol;
      f16x8 bh0 = *(const f16x8*)(&bh[mq][c0]);
      f16x8 bh1 = *(const f16x8*)(&bh[mq][32 + c0]);
      f16x8 bl0 = *(const f16x8*)(&bl[mq][c0]);
      f16x8 bl1 = *(const f16x8*)(&bl[mq][32 + c0]);
      f32x4 a2 = {0.f, 0.f, 0.f, 0.f};
      a2 = __builtin_amdgcn_mfma_f32_16x16x32_f16(a0, bh0, a2, 0, 0, 0);
      a2 = __builtin_amdgcn_mfma_f32_16x16x32_f16(a1, bh1, a2, 0, 0, 0);
      a2 = __builtin_amdgcn_mfma_f32_16x16x32_f16(a0, bl0, a2, 0, 0, 0);
      a2 = __builtin_amdgcn_mfma_f32_16x16x32_f16(a1, bl1, a2, 0, 0, 0);
      float rcp = rcp_l[mq];
      f16x4 o4;
      #pragma unroll
      for (int r = 0; r < 4; ++r) {
        float ov = a2[r] * rcp + bvv[r];
        sacc += ov; ssacc += ov * ov;
        o4[r] = (_Float16)ov;
      }
      *(f16x4*)(om + ((size_t)bf * 576 + m0 + mq) * 128 + cb * 16 + row0) = o4;
    }
  }

  #pragma unroll
  for (int off = 1; off < 64; off <<= 1) {
    sacc += __shfl_xor(sacc, off, 64);
    ssacc += __shfl_xor(ssacc, off, 64);
  }
  __shared__ float rs[4], rss[4];
  if (lane == 0) { rs[wid] = sacc; rss[wid] = ssacc; }
  __syncthreads();
  if (t == 0) {
    atomicAdd(gn_sum + (bf >> 2), rs[0] + rs[1] + rs[2] + rs[3]);
    atomicAdd(gn_ss + (bf >> 2), rss[0] + rss[1] + rss[2] + rss[3]);
  }
}

// ---------------------------------------------------------------------------
// K4: per (b, output row o2): skip conv via implicit-GEMM f16 MFMA (K=576)
//     + GroupNorm apply + unfold + add.
// ---------------------------------------------------------------------------
__global__ __launch_bounds__(256) void k4_final(
    const float* __restrict__ x, const _Float16* __restrict__ w_skip_h,
    const float* __restrict__ b_skip, const _Float16* __restrict__ om,
    const float* __restrict__ gn_sum, const float* __restrict__ gn_ss,
    const float* __restrict__ gamma, const float* __restrict__ beta,
    float* __restrict__ out)
{
  const int o2 = blockIdx.x;          // 0..47
  const int b = blockIdx.y;           // 0..15
  const int t = threadIdx.x;
  const int lane = t & 63, wid = t >> 6;

  __shared__ __align__(16) _Float16 xcol[3][2][49][72];
  __shared__ _Float16 raw[64][3][98];

  for (int i = t; i < 64 * 3 * 96; i += 256) {
    int c = i / 288, r = i % 288, dh = r / 96, col = r % 96;
    int R = 2 * o2 + dh - 1;
    float v = (R >= 0) ? x[((size_t)(b * 64 + c) * 96 + R) * 96 + col] : 0.f;
    raw[c][dh][col] = (_Float16)v;
  }
  __syncthreads();
  for (int i = t; i < 3 * 98 * 64; i += 256) {
    int c = i & 63, r = i >> 6, cc = r % 98, dh = r / 98;
    _Float16 v = (_Float16)0.f;
    if (cc >= 1 && cc <= 96) v = raw[c][dh][cc - 1];
    xcol[dh][cc & 1][cc >> 1][c] = v;
  }
  __syncthreads();

  const float Ninv = 1.0f / 294912.0f;
  const float mu = gn_sum[b] * Ninv;
  const float var = gn_ss[b] * Ninv - mu * mu;
  const float istd = rsqrtf(var + 1e-5f);
  const int f1 = o2 / 24, w24 = o2 % 24;

  const int ccol = lane & 15, row0 = (lane >> 4) * 4, c0 = (lane >> 4) * 8;

  for (int tt = wid * 6; tt < wid * 6 + 6; ++tt) {
    int mb = tt / 3, nb = tt % 3;
    f32x4 a2 = {0.f, 0.f, 0.f, 0.f};
    const _Float16* wrow = w_skip_h + (size_t)(mb * 16 + ccol) * 576;
    const int o3 = nb * 16 + ccol;
    #pragma unroll
    for (int ks = 0; ks < 18; ++ks) {
      int dd = ks >> 1;
      int dh = dd / 3, dw = dd % 3;
      int cl = (ks & 1) * 32 + c0;
      f16x8 a = *(const f16x8*)(wrow + ks * 32 + c0);
      f16x8 bb = *(const f16x8*)(&xcol[dh][dw & 1][o3 + (dw >> 1)][cl]);
      a2 = __builtin_amdgcn_mfma_f32_16x16x32_f16(a, bb, a2, 0, 0, 0);
    }
    const int f2 = o3 / 24, h = o3 % 24;
    const int bf = ((b * 2 + f1) * 2) + f2;
    const int m = w24 * 24 + h;
    #pragma unroll
    for (int r = 0; r < 4; ++r) {
      int co = mb * 16 + row0 + r;
      float om_v = (float)om[((size_t)bf * 576 + m) * 128 + co];
      float gnv = (om_v - mu) * istd * gamma[co] + beta[co];
      out[((size_t)(b * 128 + co) * 48 + o2) * 48 + o3] = a2[r] + b_skip[co] + gnv;
    }
  }
}

// ---------------------------------------------------------------------------
extern "C" void kernel_launch(void* const* d_in, const int* in_sizes, int n_in,
                              void* d_out, int out_size, void* d_ws, size_t ws_size,
                              hipStream_t stream) {
  const float* x      = (const float*)d_in[0];
  const float* w_f    = (const float*)d_in[1];
  const float* b_f    = (const float*)d_in[2];
  const float* w_v    = (const float*)d_in[3];
  const float* b_v    = (const float*)d_in[4];
  const float* w_skip = (const float*)d_in[5];
  const float* b_skip = (const float*)d_in[6];
  const float* gamma  = (const float*)d_in[7];
  const float* beta   = (const float*)d_in[8];
  float* out = (float*)d_out;

  char* ws = (char*)d_ws;
  _Float16* cenW_h   = (_Float16*)(ws);                 // 4,718,592
  _Float16* cenW_l   = (_Float16*)(ws + 4718592);       // 4,718,592
  _Float16* om       = (_Float16*)(ws);                 // aliases cenW (dead after K2)
  float*    dvec     = (float*)(ws + 9437184);          // 147,456
  float*    xc       = (float*)(ws + 9584640);          // 9,437,184
  _Float16* w_v_h    = (_Float16*)(ws + 19021824);      // 16,384
  _Float16* w_skip_h = (_Float16*)(ws + 19038208);      // 147,456
  float*    xsum     = (float*)(ws + 19185664);         // 9,437,184  [memset]
  float*    counts   = (float*)(ws + 28622848);         // 147,456    [memset]
  float*    gn_sum   = (float*)(ws + 28770304);         // 256        [memset]
  float*    gn_ss    = (float*)(ws + 28770560);         // 256        [memset]

  hipMemsetAsync(ws + 19185664, 0, 9585152, stream);

  k1_centers<<<dim3(24, 64), dim3(256), 0, stream>>>(
      x, w_f, b_f, w_v, w_skip, cenW_h, cenW_l, dvec, xc, w_v_h, w_skip_h);
  k2_assign<<<dim3(1152), dim3(256), 0, stream>>>(
      x, cenW_h, cenW_l, dvec, xsum, counts);
  k2c_pool<<<dim3(4, 64), dim3(256), 0, stream>>>(
      xsum, xc, counts, w_v_h, b_v, om, gn_sum, gn_ss);
  k4_final<<<dim3(48, 16), dim3(256), 0, stream>>>(
      x, w_skip_h, b_skip, om, gn_sum, gn_ss, gamma, beta, out);
}

// Round 3
// 324.602 us; speedup vs baseline: 2.2671x; 1.2532x over previous
//
#include <hip/hip_runtime.h>

typedef _Float16 f16x8 __attribute__((ext_vector_type(8)));
typedef _Float16 f16x4 __attribute__((ext_vector_type(4)));
typedef float f32x4 __attribute__((ext_vector_type(4)));

// ---------------------------------------------------------------------------
// K1: per (bf quadrant, wc row of 24 centers):
//   xc = 2x2-avgpool(x)  (stored for K2c);  centers = W_f xc + b_f
//   cen = centers/||centers||;  cenW[m][cin] = W_f^T cen[m] (f16 hi/lo split)
//   d[m] = cen[m]·b_f
//   side jobs: w_v -> f16, w_skip -> f16 reordered [co][dh*3+dw][cin]
// ---------------------------------------------------------------------------
__global__ __launch_bounds__(256) void k1_centers(
    const float* __restrict__ x, const float* __restrict__ w_f,
    const float* __restrict__ b_f, const float* __restrict__ w_v,
    const float* __restrict__ w_skip,
    _Float16* __restrict__ cenW_h, _Float16* __restrict__ cenW_l,
    float* __restrict__ dvec, float* __restrict__ xc_buf,
    _Float16* __restrict__ w_v_h, _Float16* __restrict__ w_skip_h)
{
  const int wc = blockIdx.x;          // 0..23
  const int bf = blockIdx.y;          // 0..63
  const int b = bf >> 2, f1 = (bf >> 1) & 1, f2 = bf & 1;
  const int t = threadIdx.x;

  __shared__ float wf[128][65];
  __shared__ float xc[24][64];
  __shared__ float cent[24][130];
  __shared__ float inv_l[24];

  for (int i = t; i < 128 * 64; i += 256) {
    int co = i >> 6, c = i & 63;
    wf[co][c] = w_f[i];
  }
  for (int e = t; e < 64 * 24; e += 256) {
    int c = e / 24, hc = e % 24;
    const float* xp = x + ((size_t)(b * 64 + c) * 96 + (f1 * 48 + 2 * wc)) * 96
                        + f2 * 48 + 2 * hc;
    xc[hc][c] = 0.25f * (xp[0] + xp[1] + xp[96] + xp[97]);
  }
  __syncthreads();
  {
    const int co = t & 127;
    const int hg = t >> 7;
    for (int p = 0; p < 12; ++p) {
      int hc = p * 2 + hg;
      float accf = b_f[co];
      #pragma unroll
      for (int c = 0; c < 64; ++c) accf = fmaf(wf[co][c], xc[hc][c], accf);
      cent[hc][co] = accf;
    }
  }
  for (int e = t; e < 24 * 64; e += 256) {
    int hc = e >> 6, c = e & 63;
    xc_buf[((size_t)bf * 576 + wc * 24 + hc) * 64 + c] = xc[hc][c];
  }
  __syncthreads();
  if (t < 24) {
    float ss = 0.f, db = 0.f;
    for (int c = 0; c < 128; ++c) { float v = cent[t][c]; ss += v * v; db += v * b_f[c]; }
    float inv = 1.0f / fmaxf(sqrtf(ss), 1e-12f);
    inv_l[t] = inv;
    dvec[bf * 576 + wc * 24 + t] = inv * db;
  }
  __syncthreads();
  for (int e = t; e < 24 * 64; e += 256) {
    int hc = e >> 6, c = e & 63;
    float acc = 0.f;
    for (int co2 = 0; co2 < 128; ++co2) acc = fmaf(cent[hc][co2], wf[co2][c], acc);
    acc *= inv_l[hc];
    _Float16 hi = (_Float16)acc;
    size_t o = ((size_t)bf * 576 + wc * 24 + hc) * 64 + c;
    cenW_h[o] = hi;
    cenW_l[o] = (_Float16)(acc - (float)hi);
  }
  if (bf == 0 && wc == 0) {
    for (int i = t; i < 128 * 64; i += 256) w_v_h[i] = (_Float16)w_v[i];
  }
  if (bf == 1) {
    for (int i = wc * 3072 + t; i < wc * 3072 + 3072; i += 256) {
      int co = i / 576, r = i % 576, dd = r >> 6, c = r & 63;
      w_skip_h[i] = (_Float16)w_skip[((co * 64 + c) * 3 + dd / 3) * 3 + (dd % 3)];
    }
  }
}

// ---------------------------------------------------------------------------
// K2: per (bf, tile of 128 points = 8 rows x 16 cols):
//   argmax_m ( cenW[m]·x[n] + d[m] ) via 3-term split f16 MFMA.
//   nb-chunked loop: B-frags register-cached, mb swept with A from L2
//   (LDS b128 reads cut 9x). Per-point winner via packed u64 LDS atomicMax.
//   Segment-sum by OWNERSHIP: each interior center gathers its 4 own points
//   (predicated); non-own points (rare, ~2%) go via compact outlier list.
//   c-block XOR swizzle (cb ^= row&3) on both stage-write and frag-read.
// ---------------------------------------------------------------------------
__global__ __launch_bounds__(256, 4) void k2_assign(
    const float* __restrict__ x,
    const _Float16* __restrict__ cenW_h, const _Float16* __restrict__ cenW_l,
    const float* __restrict__ dvec,
    float* __restrict__ xsum, float* __restrict__ counts)
{
  const int id = blockIdx.x;          // 0..1151
  const int xcd = id & 7;
  const int j = id >> 3;              // 0..143
  const int bf = xcd * 8 + j / 18;
  const int tile = j % 18;
  const int b = bf >> 2, f1 = (bf >> 1) & 1, f2 = bf & 1;
  const int t = threadIdx.x;
  const int lane = t & 63, wid = t >> 6;

  const int tr = tile / 3, tc = tile % 3;
  const int w0 = tr * 8, h0 = tc * 16;

  __shared__ __align__(16) _Float16 xh[128][72];
  __shared__ __align__(16) _Float16 xl[128][72];
  __shared__ unsigned long long key[128];
  __shared__ int idxf[128];
  __shared__ int olist[128];
  __shared__ int ocnt;

  if (t < 128) key[t] = 0ull;
  if (t == 0) ocnt = 0;

  for (int i = t; i < 64 * 128; i += 256) {
    int c = i >> 7, jj = i & 127;
    float v = x[((size_t)(b * 64 + c) * 96 + (f1 * 48 + w0 + (jj >> 4))) * 96
                + f2 * 48 + h0 + (jj & 15)];
    _Float16 hi = (_Float16)v;
    int colW = (c & 7) | ((((c >> 3) ^ (jj & 3)) & 7) << 3);
    xh[jj][colW] = hi;
    xl[jj][colW] = (_Float16)(v - (float)hi);
  }
  __syncthreads();

  const int ccol = lane & 15;
  const int g = lane >> 4;
  const int row0 = g * 4;
  const _Float16* cw_h = cenW_h + (size_t)bf * 576 * 64;
  const _Float16* cw_l = cenW_l + (size_t)bf * 576 * 64;
  const float* dv_bf = dvec + bf * 576;

  #pragma unroll
  for (int chunk = 0; chunk < 4; ++chunk) {
    const int nA = (chunk * 2) * 16 + ccol;
    const int nB = (chunk * 2 + 1) * 16 + ccol;
    // register-cached B fragments (swizzled c-block)
    const int cbA = (g ^ (nA & 3)) << 3;
    const int cbB = (g ^ (nB & 3)) << 3;
    f16x8 bhA0 = *(const f16x8*)(&xh[nA][cbA]);
    f16x8 bhA1 = *(const f16x8*)(&xh[nA][cbA + 32]);
    f16x8 blA0 = *(const f16x8*)(&xl[nA][cbA]);
    f16x8 blA1 = *(const f16x8*)(&xl[nA][cbA + 32]);
    f16x8 bhB0 = *(const f16x8*)(&xh[nB][cbB]);
    f16x8 bhB1 = *(const f16x8*)(&xh[nB][cbB + 32]);
    f16x8 blB0 = *(const f16x8*)(&xl[nB][cbB]);
    f16x8 blB1 = *(const f16x8*)(&xl[nB][cbB + 32]);

    float bvA = -3.0e38f, bvB = -3.0e38f;
    int biA = 0, biB = 0;

    for (int mb = wid; mb < 36; mb += 4) {
      const size_t abase = (size_t)(mb * 16 + ccol) * 64 + g * 8;
      f16x8 ah0 = *(const f16x8*)(cw_h + abase);
      f16x8 ah1 = *(const f16x8*)(cw_h + abase + 32);
      f16x8 al0 = *(const f16x8*)(cw_l + abase);
      f16x8 al1 = *(const f16x8*)(cw_l + abase + 32);
      f32x4 dv4 = *(const f32x4*)(dv_bf + mb * 16 + row0);

      f32x4 aA = {0.f, 0.f, 0.f, 0.f};
      f32x4 aB = {0.f, 0.f, 0.f, 0.f};
      aA = __builtin_amdgcn_mfma_f32_16x16x32_f16(ah0, bhA0, aA, 0, 0, 0);
      aB = __builtin_amdgcn_mfma_f32_16x16x32_f16(ah0, bhB0, aB, 0, 0, 0);
      aA = __builtin_amdgcn_mfma_f32_16x16x32_f16(ah1, bhA1, aA, 0, 0, 0);
      aB = __builtin_amdgcn_mfma_f32_16x16x32_f16(ah1, bhB1, aB, 0, 0, 0);
      aA = __builtin_amdgcn_mfma_f32_16x16x32_f16(ah0, blA0, aA, 0, 0, 0);
      aB = __builtin_amdgcn_mfma_f32_16x16x32_f16(ah0, blB0, aB, 0, 0, 0);
      aA = __builtin_amdgcn_mfma_f32_16x16x32_f16(ah1, blA1, aA, 0, 0, 0);
      aB = __builtin_amdgcn_mfma_f32_16x16x32_f16(ah1, blB1, aB, 0, 0, 0);
      aA = __builtin_amdgcn_mfma_f32_16x16x32_f16(al0, bhA0, aA, 0, 0, 0);
      aB = __builtin_amdgcn_mfma_f32_16x16x32_f16(al0, bhB0, aB, 0, 0, 0);
      aA = __builtin_amdgcn_mfma_f32_16x16x32_f16(al1, bhA1, aA, 0, 0, 0);
      aB = __builtin_amdgcn_mfma_f32_16x16x32_f16(al1, bhB1, aB, 0, 0, 0);

      #pragma unroll
      for (int r = 0; r < 4; ++r) {
        int m = mb * 16 + row0 + r;
        float vA = aA[r] + dv4[r];
        float vB = aB[r] + dv4[r];
        if (vA > bvA || (vA == bvA && m < biA)) { bvA = vA; biA = m; }
        if (vB > bvB || (vB == bvB && m < biB)) { bvB = vB; biB = m; }
      }
    }

    // cross-g reduce (lanes ccol, ccol+16, ccol+32, ccol+48)
    #pragma unroll
    for (int off = 16; off <= 32; off <<= 1) {
      float ov = __shfl_xor(bvA, off, 64);
      int oi = __shfl_xor(biA, off, 64);
      if (ov > bvA || (ov == bvA && oi < biA)) { bvA = ov; biA = oi; }
      ov = __shfl_xor(bvB, off, 64);
      oi = __shfl_xor(biB, off, 64);
      if (ov > bvB || (ov == bvB && oi < biB)) { bvB = ov; biB = oi; }
    }
    if (lane < 16) {
      unsigned uA = __float_as_uint(bvA);
      uA = (uA & 0x80000000u) ? ~uA : (uA | 0x80000000u);
      atomicMax(&key[nA], ((unsigned long long)uA << 10) | (unsigned)(1023 - biA));
      unsigned uB = __float_as_uint(bvB);
      uB = (uB & 0x80000000u) ? ~uB : (uB | 0x80000000u);
      atomicMax(&key[nB], ((unsigned long long)uB << 10) | (unsigned)(1023 - biB));
    }
  }
  __syncthreads();

  if (t < 128) {
    int mi = 1023 - (int)(key[t] & 1023ull);
    idxf[t] = mi;
    int own = (tr * 4 + ((t >> 4) >> 1)) * 24 + tc * 8 + ((t & 15) >> 1);
    if (mi != own) {
      int o = atomicAdd(&ocnt, 1);
      olist[o] = t;
    }
  }
  __syncthreads();

  // ownership gather: wave handles 8 interior centers, lanes = 64 channels
  for (int si = 0; si < 8; ++si) {
    const int s = wid * 8 + si;
    const int r = s >> 3, q = s & 7;
    const int m = (tr * 4 + r) * 24 + tc * 8 + q;
    const int p00 = (2 * r) * 16 + 2 * q;
    float sum = 0.f;
    int cnt = 0;
    #pragma unroll
    for (int dp = 0; dp < 4; ++dp) {
      const int p = p00 + (dp >> 1) * 16 + (dp & 1);
      if (idxf[p] == m) {
        int colW = (lane & 7) | ((((lane >> 3) ^ (p & 3)) & 7) << 3);
        sum += (float)xh[p][colW] + (float)xl[p][colW];
        ++cnt;
      }
    }
    if (cnt > 0) {
      atomicAdd(&xsum[((size_t)bf * 576 + m) * 64 + lane], sum);
      if (lane == 0) atomicAdd(&counts[bf * 576 + m], (float)cnt);
    }
  }

  // outliers (rare): wave per outlier point, lanes = channels
  for (int o = wid; o < ocnt; o += 4) {
    const int p = olist[o];
    const int m = idxf[p];
    int colW = (lane & 7) | ((((lane >> 3) ^ (p & 3)) & 7) << 3);
    float v = (float)xh[p][colW] + (float)xl[p][colW];
    atomicAdd(&xsum[((size_t)bf * 576 + m) * 64 + lane], v);
    if (lane == 0) atomicAdd(&counts[bf * 576 + m], 1.0f);
  }
}

// ---------------------------------------------------------------------------
// K2c: pooled GEMM + divide + GroupNorm stats:
//   om[m][co] = (W_v·(xsum[m]+xc[m]))/(cnt[m]+1) + b_v[co]   (f16 out)
//   gn_sum/gn_ss += per-b partial sums of om.
// ---------------------------------------------------------------------------
__global__ __launch_bounds__(256) void k2c_pool(
    const float* __restrict__ xsum, const float* __restrict__ xc,
    const float* __restrict__ counts, const _Float16* __restrict__ w_v_h,
    const float* __restrict__ b_v, _Float16* __restrict__ om,
    float* __restrict__ gn_sum, float* __restrict__ gn_ss)
{
  const int chunk = blockIdx.x;       // 0..3
  const int bf = blockIdx.y;          // 0..63
  const int m0 = chunk * 144;
  const int t = threadIdx.x;
  const int lane = t & 63, wid = t >> 6;

  __shared__ __align__(16) _Float16 bh[144][72];
  __shared__ __align__(16) _Float16 bl[144][72];
  __shared__ float rcp_l[144];

  for (int i = t; i < 144 * 64; i += 256) {
    int mq = i >> 6, c = i & 63;
    size_t gdx = ((size_t)bf * 576 + m0 + mq) * 64 + c;
    float s = xsum[gdx] + xc[gdx];
    _Float16 hi = (_Float16)s;
    bh[mq][c] = hi;
    bl[mq][c] = (_Float16)(s - (float)hi);
  }
  if (t < 144) rcp_l[t] = 1.0f / (counts[bf * 576 + m0 + t] + 1.0f);
  __syncthreads();

  const int ccol = lane & 15, row0 = (lane >> 4) * 4, c0 = (lane >> 4) * 8;
  float sacc = 0.f, ssacc = 0.f;

  #pragma unroll
  for (int cbi = 0; cbi < 2; ++cbi) {
    const int cb = wid + cbi * 4;
    const size_t abase = (size_t)(cb * 16 + ccol) * 64;
    f16x8 a0 = *(const f16x8*)(w_v_h + abase + c0);
    f16x8 a1 = *(const f16x8*)(w_v_h + abase + 32 + c0);
    float bvv[4];
    #pragma unroll
    for (int r = 0; r < 4; ++r) bvv[r] = b_v[cb * 16 + row0 + r];
    for (int nb = 0; nb < 9; ++nb) {
      int mq = nb * 16 + ccol;
      f16x8 bh0 = *(const f16x8*)(&bh[mq][c0]);
      f16x8 bh1 = *(const f16x8*)(&bh[mq][32 + c0]);
      f16x8 bl0 = *(const f16x8*)(&bl[mq][c0]);
      f16x8 bl1 = *(const f16x8*)(&bl[mq][32 + c0]);
      f32x4 a2 = {0.f, 0.f, 0.f, 0.f};
      a2 = __builtin_amdgcn_mfma_f32_16x16x32_f16(a0, bh0, a2, 0, 0, 0);
      a2 = __builtin_amdgcn_mfma_f32_16x16x32_f16(a1, bh1, a2, 0, 0, 0);
      a2 = __builtin_amdgcn_mfma_f32_16x16x32_f16(a0, bl0, a2, 0, 0, 0);
      a2 = __builtin_amdgcn_mfma_f32_16x16x32_f16(a1, bl1, a2, 0, 0, 0);
      float rcp = rcp_l[mq];
      f16x4 o4;
      #pragma unroll
      for (int r = 0; r < 4; ++r) {
        float ov = a2[r] * rcp + bvv[r];
        sacc += ov; ssacc += ov * ov;
        o4[r] = (_Float16)ov;
      }
      *(f16x4*)(om + ((size_t)bf * 576 + m0 + mq) * 128 + cb * 16 + row0) = o4;
    }
  }

  #pragma unroll
  for (int off = 1; off < 64; off <<= 1) {
    sacc += __shfl_xor(sacc, off, 64);
    ssacc += __shfl_xor(ssacc, off, 64);
  }
  __shared__ float rs[4], rss[4];
  if (lane == 0) { rs[wid] = sacc; rss[wid] = ssacc; }
  __syncthreads();
  if (t == 0) {
    atomicAdd(gn_sum + (bf >> 2), rs[0] + rs[1] + rs[2] + rs[3]);
    atomicAdd(gn_ss + (bf >> 2), rss[0] + rss[1] + rss[2] + rss[3]);
  }
}

// ---------------------------------------------------------------------------
// K4: per (b, output row o2): skip conv via implicit-GEMM f16 MFMA (K=576)
//     + GroupNorm apply + unfold + add.
// ---------------------------------------------------------------------------
__global__ __launch_bounds__(256) void k4_final(
    const float* __restrict__ x, const _Float16* __restrict__ w_skip_h,
    const float* __restrict__ b_skip, const _Float16* __restrict__ om,
    const float* __restrict__ gn_sum, const float* __restrict__ gn_ss,
    const float* __restrict__ gamma, const float* __restrict__ beta,
    float* __restrict__ out)
{
  const int o2 = blockIdx.x;          // 0..47
  const int b = blockIdx.y;           // 0..15
  const int t = threadIdx.x;
  const int lane = t & 63, wid = t >> 6;

  __shared__ __align__(16) _Float16 xcol[3][2][49][72];
  __shared__ _Float16 raw[64][3][98];

  for (int i = t; i < 64 * 3 * 96; i += 256) {
    int c = i / 288, r = i % 288, dh = r / 96, col = r % 96;
    int R = 2 * o2 + dh - 1;
    float v = (R >= 0) ? x[((size_t)(b * 64 + c) * 96 + R) * 96 + col] : 0.f;
    raw[c][dh][col] = (_Float16)v;
  }
  __syncthreads();
  for (int i = t; i < 3 * 98 * 64; i += 256) {
    int c = i & 63, r = i >> 6, cc = r % 98, dh = r / 98;
    _Float16 v = (_Float16)0.f;
    if (cc >= 1 && cc <= 96) v = raw[c][dh][cc - 1];
    xcol[dh][cc & 1][cc >> 1][c] = v;
  }
  __syncthreads();

  const float Ninv = 1.0f / 294912.0f;
  const float mu = gn_sum[b] * Ninv;
  const float var = gn_ss[b] * Ninv - mu * mu;
  const float istd = rsqrtf(var + 1e-5f);
  const int f1 = o2 / 24, w24 = o2 % 24;

  const int ccol = lane & 15, row0 = (lane >> 4) * 4, c0 = (lane >> 4) * 8;

  for (int tt = wid * 6; tt < wid * 6 + 6; ++tt) {
    int mb = tt / 3, nb = tt % 3;
    f32x4 a2 = {0.f, 0.f, 0.f, 0.f};
    const _Float16* wrow = w_skip_h + (size_t)(mb * 16 + ccol) * 576;
    const int o3 = nb * 16 + ccol;
    #pragma unroll
    for (int ks = 0; ks < 18; ++ks) {
      int dd = ks >> 1;
      int dh = dd / 3, dw = dd % 3;
      int cl = (ks & 1) * 32 + c0;
      f16x8 a = *(const f16x8*)(wrow + ks * 32 + c0);
      f16x8 bb = *(const f16x8*)(&xcol[dh][dw & 1][o3 + (dw >> 1)][cl]);
      a2 = __builtin_amdgcn_mfma_f32_16x16x32_f16(a, bb, a2, 0, 0, 0);
    }
    const int f2 = o3 / 24, h = o3 % 24;
    const int bf = ((b * 2 + f1) * 2) + f2;
    const int m = w24 * 24 + h;
    #pragma unroll
    for (int r = 0; r < 4; ++r) {
      int co = mb * 16 + row0 + r;
      float om_v = (float)om[((size_t)bf * 576 + m) * 128 + co];
      float gnv = (om_v - mu) * istd * gamma[co] + beta[co];
      out[((size_t)(b * 128 + co) * 48 + o2) * 48 + o3] = a2[r] + b_skip[co] + gnv;
    }
  }
}

// ---------------------------------------------------------------------------
extern "C" void kernel_launch(void* const* d_in, const int* in_sizes, int n_in,
                              void* d_out, int out_size, void* d_ws, size_t ws_size,
                              hipStream_t stream) {
  const float* x      = (const float*)d_in[0];
  const float* w_f    = (const float*)d_in[1];
  const float* b_f    = (const float*)d_in[2];
  const float* w_v    = (const float*)d_in[3];
  const float* b_v    = (const float*)d_in[4];
  const float* w_skip = (const float*)d_in[5];
  const float* b_skip = (const float*)d_in[6];
  const float* gamma  = (const float*)d_in[7];
  const float* beta   = (const float*)d_in[8];
  float* out = (float*)d_out;

  char* ws = (char*)d_ws;
  _Float16* cenW_h   = (_Float16*)(ws);                 // 4,718,592
  _Float16* cenW_l   = (_Float16*)(ws + 4718592);       // 4,718,592
  _Float16* om       = (_Float16*)(ws);                 // aliases cenW (dead after K2)
  float*    dvec     = (float*)(ws + 9437184);          // 147,456
  float*    xc       = (float*)(ws + 9584640);          // 9,437,184
  _Float16* w_v_h    = (_Float16*)(ws + 19021824);      // 16,384
  _Float16* w_skip_h = (_Float16*)(ws + 19038208);      // 147,456
  float*    xsum     = (float*)(ws + 19185664);         // 9,437,184  [memset]
  float*    counts   = (float*)(ws + 28622848);         // 147,456    [memset]
  float*    gn_sum   = (float*)(ws + 28770304);         // 256        [memset]
  float*    gn_ss    = (float*)(ws + 28770560);         // 256        [memset]

  hipMemsetAsync(ws + 19185664, 0, 9585152, stream);

  k1_centers<<<dim3(24, 64), dim3(256), 0, stream>>>(
      x, w_f, b_f, w_v, w_skip, cenW_h, cenW_l, dvec, xc, w_v_h, w_skip_h);
  k2_assign<<<dim3(1152), dim3(256), 0, stream>>>(
      x, cenW_h, cenW_l, dvec, xsum, counts);
  k2c_pool<<<dim3(4, 64), dim3(256), 0, stream>>>(
      xsum, xc, counts, w_v_h, b_v, om, gn_sum, gn_ss);
  k4_final<<<dim3(48, 16), dim3(256), 0, stream>>>(
      x, w_skip_h, b_skip, om, gn_sum, gn_ss, gamma, beta, out);
}

// Round 4
// 311.604 us; speedup vs baseline: 2.3617x; 1.0417x over previous
//
#include <hip/hip_runtime.h>

typedef _Float16 f16x8 __attribute__((ext_vector_type(8)));
typedef _Float16 f16x4 __attribute__((ext_vector_type(4)));
typedef float f32x4 __attribute__((ext_vector_type(4)));

// ---------------------------------------------------------------------------
// K1: per (bf quadrant, wc row of 24 centers):
//   xc = 2x2-avgpool(x)  (stored for K2c);  centers = W_f xc + b_f
//   cen = centers/||centers||;  cenW[m][cin] = W_f^T cen[m] (f16 hi/lo split)
//   d[m] = cen[m]·b_f
//   side jobs: w_v -> f16, w_skip -> f16 reordered [co][dh*3+dw][cin]
// ---------------------------------------------------------------------------
__global__ __launch_bounds__(256) void k1_centers(
    const float* __restrict__ x, const float* __restrict__ w_f,
    const float* __restrict__ b_f, const float* __restrict__ w_v,
    const float* __restrict__ w_skip,
    _Float16* __restrict__ cenW_h, _Float16* __restrict__ cenW_l,
    float* __restrict__ dvec, float* __restrict__ xc_buf,
    _Float16* __restrict__ w_v_h, _Float16* __restrict__ w_skip_h)
{
  const int wc = blockIdx.x;          // 0..23
  const int bf = blockIdx.y;          // 0..63
  const int b = bf >> 2, f1 = (bf >> 1) & 1, f2 = bf & 1;
  const int t = threadIdx.x;

  __shared__ float wf[128][65];
  __shared__ float xc[24][64];
  __shared__ float cent[24][130];
  __shared__ float inv_l[24];

  for (int i = t; i < 128 * 64; i += 256) {
    int co = i >> 6, c = i & 63;
    wf[co][c] = w_f[i];
  }
  for (int e = t; e < 64 * 24; e += 256) {
    int c = e / 24, hc = e % 24;
    const float* xp = x + ((size_t)(b * 64 + c) * 96 + (f1 * 48 + 2 * wc)) * 96
                        + f2 * 48 + 2 * hc;
    xc[hc][c] = 0.25f * (xp[0] + xp[1] + xp[96] + xp[97]);
  }
  __syncthreads();
  {
    const int co = t & 127;
    const int hg = t >> 7;
    for (int p = 0; p < 12; ++p) {
      int hc = p * 2 + hg;
      float accf = b_f[co];
      #pragma unroll
      for (int c = 0; c < 64; ++c) accf = fmaf(wf[co][c], xc[hc][c], accf);
      cent[hc][co] = accf;
    }
  }
  for (int e = t; e < 24 * 64; e += 256) {
    int hc = e >> 6, c = e & 63;
    xc_buf[((size_t)bf * 576 + wc * 24 + hc) * 64 + c] = xc[hc][c];
  }
  __syncthreads();
  if (t < 24) {
    float ss = 0.f, db = 0.f;
    for (int c = 0; c < 128; ++c) { float v = cent[t][c]; ss += v * v; db += v * b_f[c]; }
    float inv = 1.0f / fmaxf(sqrtf(ss), 1e-12f);
    inv_l[t] = inv;
    dvec[bf * 576 + wc * 24 + t] = inv * db;
  }
  __syncthreads();
  for (int e = t; e < 24 * 64; e += 256) {
    int hc = e >> 6, c = e & 63;
    float acc = 0.f;
    for (int co2 = 0; co2 < 128; ++co2) acc = fmaf(cent[hc][co2], wf[co2][c], acc);
    acc *= inv_l[hc];
    _Float16 hi = (_Float16)acc;
    size_t o = ((size_t)bf * 576 + wc * 24 + hc) * 64 + c;
    cenW_h[o] = hi;
    cenW_l[o] = (_Float16)(acc - (float)hi);
  }
  if (bf == 0 && wc == 0) {
    for (int i = t; i < 128 * 64; i += 256) w_v_h[i] = (_Float16)w_v[i];
  }
  if (bf == 1) {
    for (int i = wc * 3072 + t; i < wc * 3072 + 3072; i += 256) {
      int co = i / 576, r = i % 576, dd = r >> 6, c = r & 63;
      w_skip_h[i] = (_Float16)w_skip[((co * 64 + c) * 3 + dd / 3) * 3 + (dd % 3)];
    }
  }
}

// ---------------------------------------------------------------------------
// K2: per (bf, tile of 128 points = 8 rows x 16 cols):
//   x staged as f32 xs[128][65] (conflict-free both directions).
//   Each wave owns 2 n-blocks: B hi/lo f16 fragments built once in registers,
//   then a single mb=0..35 sweep with A streamed from L2 (12 MFMA / 64B/lane),
//   dvec folded into the MFMA C-init. No cross-wave argmax, no LDS keys.
//   Segment-sum by ownership gather from xs (f32 exact); rare outliers via
//   compact list. XCD-affinity block swizzle for L2-local atomics.
// ---------------------------------------------------------------------------
__global__ __launch_bounds__(256, 4) void k2_assign(
    const float* __restrict__ x,
    const _Float16* __restrict__ cenW_h, const _Float16* __restrict__ cenW_l,
    const float* __restrict__ dvec,
    float* __restrict__ xsum, float* __restrict__ counts)
{
  const int id = blockIdx.x;          // 0..1151
  const int xcd = id & 7;
  const int j = id >> 3;              // 0..143
  const int bf = xcd * 8 + j / 18;
  const int tile = j % 18;
  const int b = bf >> 2, f1 = (bf >> 1) & 1, f2 = bf & 1;
  const int t = threadIdx.x;
  const int lane = t & 63, wid = t >> 6;

  const int tr = tile / 3, tc = tile % 3;
  const int w0 = tr * 8, h0 = tc * 16;

  __shared__ float xs[128][65];
  __shared__ int idxf[128];
  __shared__ int olist[128];
  __shared__ int ocnt;

  if (t == 0) ocnt = 0;

  for (int i = t; i < 64 * 128; i += 256) {
    int c = i >> 7, jj = i & 127;
    xs[jj][c] = x[((size_t)(b * 64 + c) * 96 + (f1 * 48 + w0 + (jj >> 4))) * 96
                  + f2 * 48 + h0 + (jj & 15)];
  }
  __syncthreads();

  const int ccol = lane & 15;
  const int g = lane >> 4;

  // B fragments (2 n-blocks per wave), hi/lo split computed in VALU
  f16x8 bh[2][2], bl[2][2];
  #pragma unroll
  for (int q = 0; q < 2; ++q) {
    const int p = (wid * 2 + q) * 16 + ccol;
    #pragma unroll
    for (int kf = 0; kf < 2; ++kf) {
      f16x8 hv, lv;
      #pragma unroll
      for (int e = 0; e < 8; ++e) {
        float v = xs[p][kf * 32 + g * 8 + e];
        _Float16 hi = (_Float16)v;
        hv[e] = hi;
        lv[e] = (_Float16)(v - (float)hi);
      }
      bh[q][kf] = hv; bl[q][kf] = lv;
    }
  }

  const _Float16* cw_h = cenW_h + (size_t)bf * 576 * 64;
  const _Float16* cw_l = cenW_l + (size_t)bf * 576 * 64;
  const float* dv_bf = dvec + bf * 576;
  const int arow = ccol * 64 + g * 8;

  float bv0 = -3.0e38f, bv1 = -3.0e38f;
  int bi0 = 0, bi1 = 0;

  #pragma unroll 2
  for (int mb = 0; mb < 36; ++mb) {
    const size_t abase = (size_t)mb * 1024 + arow;
    f16x8 ah0 = *(const f16x8*)(cw_h + abase);
    f16x8 ah1 = *(const f16x8*)(cw_h + abase + 32);
    f16x8 al0 = *(const f16x8*)(cw_l + abase);
    f16x8 al1 = *(const f16x8*)(cw_l + abase + 32);
    f32x4 dv4 = *(const f32x4*)(dv_bf + mb * 16 + g * 4);

    f32x4 p0 = dv4, q0 = {0.f, 0.f, 0.f, 0.f};
    f32x4 p1 = dv4, q1 = {0.f, 0.f, 0.f, 0.f};
    p0 = __builtin_amdgcn_mfma_f32_16x16x32_f16(ah0, bh[0][0], p0, 0, 0, 0);
    q0 = __builtin_amdgcn_mfma_f32_16x16x32_f16(ah1, bh[0][1], q0, 0, 0, 0);
    p1 = __builtin_amdgcn_mfma_f32_16x16x32_f16(ah0, bh[1][0], p1, 0, 0, 0);
    q1 = __builtin_amdgcn_mfma_f32_16x16x32_f16(ah1, bh[1][1], q1, 0, 0, 0);
    p0 = __builtin_amdgcn_mfma_f32_16x16x32_f16(ah0, bl[0][0], p0, 0, 0, 0);
    q0 = __builtin_amdgcn_mfma_f32_16x16x32_f16(ah1, bl[0][1], q0, 0, 0, 0);
    p1 = __builtin_amdgcn_mfma_f32_16x16x32_f16(ah0, bl[1][0], p1, 0, 0, 0);
    q1 = __builtin_amdgcn_mfma_f32_16x16x32_f16(ah1, bl[1][1], q1, 0, 0, 0);
    p0 = __builtin_amdgcn_mfma_f32_16x16x32_f16(al0, bh[0][0], p0, 0, 0, 0);
    q0 = __builtin_amdgcn_mfma_f32_16x16x32_f16(al1, bh[0][1], q0, 0, 0, 0);
    p1 = __builtin_amdgcn_mfma_f32_16x16x32_f16(al0, bh[1][0], p1, 0, 0, 0);
    q1 = __builtin_amdgcn_mfma_f32_16x16x32_f16(al1, bh[1][1], q1, 0, 0, 0);

    f32x4 v0 = p0 + q0;
    f32x4 v1 = p1 + q1;
    #pragma unroll
    for (int r = 0; r < 4; ++r) {
      int m = mb * 16 + g * 4 + r;
      float a = v0[r];
      if (a > bv0 || (a == bv0 && m < bi0)) { bv0 = a; bi0 = m; }
      float c2 = v1[r];
      if (c2 > bv1 || (c2 == bv1 && m < bi1)) { bv1 = c2; bi1 = m; }
    }
  }

  #pragma unroll
  for (int off = 16; off <= 32; off <<= 1) {
    float ov = __shfl_xor(bv0, off, 64); int oi = __shfl_xor(bi0, off, 64);
    if (ov > bv0 || (ov == bv0 && oi < bi0)) { bv0 = ov; bi0 = oi; }
    ov = __shfl_xor(bv1, off, 64); oi = __shfl_xor(bi1, off, 64);
    if (ov > bv1 || (ov == bv1 && oi < bi1)) { bv1 = ov; bi1 = oi; }
  }
  if (lane < 16) {
    idxf[(wid * 2) * 16 + ccol] = bi0;
    idxf[(wid * 2 + 1) * 16 + ccol] = bi1;
  }
  __syncthreads();

  if (t < 128) {
    int mi = idxf[t];
    int own = (tr * 4 + ((t >> 4) >> 1)) * 24 + tc * 8 + ((t & 15) >> 1);
    if (mi != own) { int o = atomicAdd(&ocnt, 1); olist[o] = t; }
  }
  __syncthreads();

  // ownership gather: wave handles 8 interior centers, lanes = 64 channels
  for (int si = 0; si < 8; ++si) {
    const int s = wid * 8 + si;
    const int r = s >> 3, q = s & 7;
    const int m = (tr * 4 + r) * 24 + tc * 8 + q;
    const int p00 = (2 * r) * 16 + 2 * q;
    float sum = 0.f;
    int cnt = 0;
    #pragma unroll
    for (int dp = 0; dp < 4; ++dp) {
      const int p = p00 + (dp >> 1) * 16 + (dp & 1);
      if (idxf[p] == m) { sum += xs[p][lane]; ++cnt; }
    }
    if (cnt > 0) {
      atomicAdd(&xsum[((size_t)bf * 576 + m) * 64 + lane], sum);
      if (lane == 0) atomicAdd(&counts[bf * 576 + m], (float)cnt);
    }
  }

  // outliers (rare): wave per outlier point, lanes = channels
  for (int o = wid; o < ocnt; o += 4) {
    const int p = olist[o];
    const int m = idxf[p];
    atomicAdd(&xsum[((size_t)bf * 576 + m) * 64 + lane], xs[p][lane]);
    if (lane == 0) atomicAdd(&counts[bf * 576 + m], 1.0f);
  }
}

// ---------------------------------------------------------------------------
// K2c: pooled GEMM + divide + GroupNorm stats:
//   om[m][co] = (W_v·(xsum[m]+xc[m]))/(cnt[m]+1) + b_v[co]   (f16 out)
//   gn_sum/gn_ss += per-b partial sums of om.
// ---------------------------------------------------------------------------
__global__ __launch_bounds__(256) void k2c_pool(
    const float* __restrict__ xsum, const float* __restrict__ xc,
    const float* __restrict__ counts, const _Float16* __restrict__ w_v_h,
    const float* __restrict__ b_v, _Float16* __restrict__ om,
    float* __restrict__ gn_sum, float* __restrict__ gn_ss)
{
  const int chunk = blockIdx.x;       // 0..3
  const int bf = blockIdx.y;          // 0..63
  const int m0 = chunk * 144;
  const int t = threadIdx.x;
  const int lane = t & 63, wid = t >> 6;

  __shared__ __align__(16) _Float16 bh[144][72];
  __shared__ __align__(16) _Float16 bl[144][72];
  __shared__ float rcp_l[144];

  for (int i = t; i < 144 * 64; i += 256) {
    int mq = i >> 6, c = i & 63;
    size_t gdx = ((size_t)bf * 576 + m0 + mq) * 64 + c;
    float s = xsum[gdx] + xc[gdx];
    _Float16 hi = (_Float16)s;
    bh[mq][c] = hi;
    bl[mq][c] = (_Float16)(s - (float)hi);
  }
  if (t < 144) rcp_l[t] = 1.0f / (counts[bf * 576 + m0 + t] + 1.0f);
  __syncthreads();

  const int ccol = lane & 15, row0 = (lane >> 4) * 4, c0 = (lane >> 4) * 8;
  float sacc = 0.f, ssacc = 0.f;

  #pragma unroll
  for (int cbi = 0; cbi < 2; ++cbi) {
    const int cb = wid + cbi * 4;
    const size_t abase = (size_t)(cb * 16 + ccol) * 64;
    f16x8 a0 = *(const f16x8*)(w_v_h + abase + c0);
    f16x8 a1 = *(const f16x8*)(w_v_h + abase + 32 + c0);
    float bvv[4];
    #pragma unroll
    for (int r = 0; r < 4; ++r) bvv[r] = b_v[cb * 16 + row0 + r];
    for (int nb = 0; nb < 9; ++nb) {
      int mq = nb * 16 + ccol;
      f16x8 bh0 = *(const f16x8*)(&bh[mq][c0]);
      f16x8 bh1 = *(const f16x8*)(&bh[mq][32 + c0]);
      f16x8 bl0 = *(const f16x8*)(&bl[mq][c0]);
      f16x8 bl1 = *(const f16x8*)(&bl[mq][32 + c0]);
      f32x4 a2 = {0.f, 0.f, 0.f, 0.f};
      a2 = __builtin_amdgcn_mfma_f32_16x16x32_f16(a0, bh0, a2, 0, 0, 0);
      a2 = __builtin_amdgcn_mfma_f32_16x16x32_f16(a1, bh1, a2, 0, 0, 0);
      a2 = __builtin_amdgcn_mfma_f32_16x16x32_f16(a0, bl0, a2, 0, 0, 0);
      a2 = __builtin_amdgcn_mfma_f32_16x16x32_f16(a1, bl1, a2, 0, 0, 0);
      float rcp = rcp_l[mq];
      f16x4 o4;
      #pragma unroll
      for (int r = 0; r < 4; ++r) {
        float ov = a2[r] * rcp + bvv[r];
        sacc += ov; ssacc += ov * ov;
        o4[r] = (_Float16)ov;
      }
      *(f16x4*)(om + ((size_t)bf * 576 + m0 + mq) * 128 + cb * 16 + row0) = o4;
    }
  }

  #pragma unroll
  for (int off = 1; off < 64; off <<= 1) {
    sacc += __shfl_xor(sacc, off, 64);
    ssacc += __shfl_xor(ssacc, off, 64);
  }
  __shared__ float rs[4], rss[4];
  if (lane == 0) { rs[wid] = sacc; rss[wid] = ssacc; }
  __syncthreads();
  if (t == 0) {
    atomicAdd(gn_sum + (bf >> 2), rs[0] + rs[1] + rs[2] + rs[3]);
    atomicAdd(gn_ss + (bf >> 2), rss[0] + rss[1] + rss[2] + rss[3]);
  }
}

// ---------------------------------------------------------------------------
// K4: per (b, output row o2): skip conv via implicit-GEMM f16 MFMA (K=576)
//     + GroupNorm apply + unfold + add.
// ---------------------------------------------------------------------------
__global__ __launch_bounds__(256) void k4_final(
    const float* __restrict__ x, const _Float16* __restrict__ w_skip_h,
    const float* __restrict__ b_skip, const _Float16* __restrict__ om,
    const float* __restrict__ gn_sum, const float* __restrict__ gn_ss,
    const float* __restrict__ gamma, const float* __restrict__ beta,
    float* __restrict__ out)
{
  const int o2 = blockIdx.x;          // 0..47
  const int b = blockIdx.y;           // 0..15
  const int t = threadIdx.x;
  const int lane = t & 63, wid = t >> 6;

  __shared__ __align__(16) _Float16 xcol[3][2][49][72];
  __shared__ _Float16 raw[64][3][98];

  for (int i = t; i < 64 * 3 * 96; i += 256) {
    int c = i / 288, r = i % 288, dh = r / 96, col = r % 96;
    int R = 2 * o2 + dh - 1;
    float v = (R >= 0) ? x[((size_t)(b * 64 + c) * 96 + R) * 96 + col] : 0.f;
    raw[c][dh][col] = (_Float16)v;
  }
  __syncthreads();
  for (int i = t; i < 3 * 98 * 64; i += 256) {
    int c = i & 63, r = i >> 6, cc = r % 98, dh = r / 98;
    _Float16 v = (_Float16)0.f;
    if (cc >= 1 && cc <= 96) v = raw[c][dh][cc - 1];
    xcol[dh][cc & 1][cc >> 1][c] = v;
  }
  __syncthreads();

  const float Ninv = 1.0f / 294912.0f;
  const float mu = gn_sum[b] * Ninv;
  const float var = gn_ss[b] * Ninv - mu * mu;
  const float istd = rsqrtf(var + 1e-5f);
  const int f1 = o2 / 24, w24 = o2 % 24;

  const int ccol = lane & 15, row0 = (lane >> 4) * 4, c0 = (lane >> 4) * 8;

  for (int tt = wid * 6; tt < wid * 6 + 6; ++tt) {
    int mb = tt / 3, nb = tt % 3;
    f32x4 a2 = {0.f, 0.f, 0.f, 0.f};
    const _Float16* wrow = w_skip_h + (size_t)(mb * 16 + ccol) * 576;
    const int o3 = nb * 16 + ccol;
    #pragma unroll
    for (int ks = 0; ks < 18; ++ks) {
      int dd = ks >> 1;
      int dh = dd / 3, dw = dd % 3;
      int cl = (ks & 1) * 32 + c0;
      f16x8 a = *(const f16x8*)(wrow + ks * 32 + c0);
      f16x8 bb = *(const f16x8*)(&xcol[dh][dw & 1][o3 + (dw >> 1)][cl]);
      a2 = __builtin_amdgcn_mfma_f32_16x16x32_f16(a, bb, a2, 0, 0, 0);
    }
    const int f2 = o3 / 24, h = o3 % 24;
    const int bf = ((b * 2 + f1) * 2) + f2;
    const int m = w24 * 24 + h;
    #pragma unroll
    for (int r = 0; r < 4; ++r) {
      int co = mb * 16 + row0 + r;
      float om_v = (float)om[((size_t)bf * 576 + m) * 128 + co];
      float gnv = (om_v - mu) * istd * gamma[co] + beta[co];
      out[((size_t)(b * 128 + co) * 48 + o2) * 48 + o3] = a2[r] + b_skip[co] + gnv;
    }
  }
}

// ---------------------------------------------------------------------------
extern "C" void kernel_launch(void* const* d_in, const int* in_sizes, int n_in,
                              void* d_out, int out_size, void* d_ws, size_t ws_size,
                              hipStream_t stream) {
  const float* x      = (const float*)d_in[0];
  const float* w_f    = (const float*)d_in[1];
  const float* b_f    = (const float*)d_in[2];
  const float* w_v    = (const float*)d_in[3];
  const float* b_v    = (const float*)d_in[4];
  const float* w_skip = (const float*)d_in[5];
  const float* b_skip = (const float*)d_in[6];
  const float* gamma  = (const float*)d_in[7];
  const float* beta   = (const float*)d_in[8];
  float* out = (float*)d_out;

  char* ws = (char*)d_ws;
  _Float16* cenW_h   = (_Float16*)(ws);                 // 4,718,592
  _Float16* cenW_l   = (_Float16*)(ws + 4718592);       // 4,718,592
  _Float16* om       = (_Float16*)(ws);                 // aliases cenW (dead after K2)
  float*    dvec     = (float*)(ws + 9437184);          // 147,456
  float*    xc       = (float*)(ws + 9584640);          // 9,437,184
  _Float16* w_v_h    = (_Float16*)(ws + 19021824);      // 16,384
  _Float16* w_skip_h = (_Float16*)(ws + 19038208);      // 147,456
  float*    xsum     = (float*)(ws + 19185664);         // 9,437,184  [memset]
  float*    counts   = (float*)(ws + 28622848);         // 147,456    [memset]
  float*    gn_sum   = (float*)(ws + 28770304);         // 256        [memset]
  float*    gn_ss    = (float*)(ws + 28770560);         // 256        [memset]

  hipMemsetAsync(ws + 19185664, 0, 9585152, stream);

  k1_centers<<<dim3(24, 64), dim3(256), 0, stream>>>(
      x, w_f, b_f, w_v, w_skip, cenW_h, cenW_l, dvec, xc, w_v_h, w_skip_h);
  k2_assign<<<dim3(1152), dim3(256), 0, stream>>>(
      x, cenW_h, cenW_l, dvec, xsum, counts);
  k2c_pool<<<dim3(4, 64), dim3(256), 0, stream>>>(
      xsum, xc, counts, w_v_h, b_v, om, gn_sum, gn_ss);
  k4_final<<<dim3(48, 16), dim3(256), 0, stream>>>(
      x, w_skip_h, b_skip, om, gn_sum, gn_ss, gamma, beta, out);
}

// Round 5
// 256.819 us; speedup vs baseline: 2.8655x; 1.2133x over previous
//
#include <hip/hip_runtime.h>

typedef _Float16 f16x8 __attribute__((ext_vector_type(8)));
typedef _Float16 f16x4 __attribute__((ext_vector_type(4)));
typedef float f32x4 __attribute__((ext_vector_type(4)));

// ---------------------------------------------------------------------------
// K1: per (bf quadrant, wc row of 24 centers):
//   xc = 2x2-avgpool(x)  (stored for K2c);  centers = W_f xc + b_f
//   cen = centers/||centers||;  cenW[m][cin] = W_f^T cen[m], written in
//   MFMA-fragment-major f16 hi/lo layout: [bf][mb][j:h0,h1,l0,l1][lane][8]
//   d[m] = cen[m]·b_f
//   side jobs: w_v -> f16, w_skip -> f16 reordered [co][dh*3+dw][cin]
// ---------------------------------------------------------------------------
__global__ __launch_bounds__(256) void k1_centers(
    const float* __restrict__ x, const float* __restrict__ w_f,
    const float* __restrict__ b_f, const float* __restrict__ w_v,
    const float* __restrict__ w_skip,
    _Float16* __restrict__ cenW,
    float* __restrict__ dvec, float* __restrict__ xc_buf,
    _Float16* __restrict__ w_v_h, _Float16* __restrict__ w_skip_h)
{
  const int wc = blockIdx.x;          // 0..23
  const int bf = blockIdx.y;          // 0..63
  const int b = bf >> 2, f1 = (bf >> 1) & 1, f2 = bf & 1;
  const int t = threadIdx.x;

  __shared__ float wf[128][65];
  __shared__ float xc[24][64];
  __shared__ float cent[24][130];
  __shared__ float inv_l[24];

  for (int i = t; i < 128 * 64; i += 256) {
    int co = i >> 6, c = i & 63;
    wf[co][c] = w_f[i];
  }
  for (int e = t; e < 64 * 24; e += 256) {
    int c = e / 24, hc = e % 24;
    const float* xp = x + ((size_t)(b * 64 + c) * 96 + (f1 * 48 + 2 * wc)) * 96
                        + f2 * 48 + 2 * hc;
    xc[hc][c] = 0.25f * (xp[0] + xp[1] + xp[96] + xp[97]);
  }
  __syncthreads();
  {
    const int co = t & 127;
    const int hg = t >> 7;
    for (int p = 0; p < 12; ++p) {
      int hc = p * 2 + hg;
      float accf = b_f[co];
      #pragma unroll
      for (int c = 0; c < 64; ++c) accf = fmaf(wf[co][c], xc[hc][c], accf);
      cent[hc][co] = accf;
    }
  }
  for (int e = t; e < 24 * 64; e += 256) {
    int hc = e >> 6, c = e & 63;
    xc_buf[((size_t)bf * 576 + wc * 24 + hc) * 64 + c] = xc[hc][c];
  }
  __syncthreads();
  if (t < 24) {
    float ss = 0.f, db = 0.f;
    for (int c = 0; c < 128; ++c) { float v = cent[t][c]; ss += v * v; db += v * b_f[c]; }
    float inv = 1.0f / fmaxf(sqrtf(ss), 1e-12f);
    inv_l[t] = inv;
    dvec[bf * 576 + wc * 24 + t] = inv * db;
  }
  __syncthreads();
  for (int e = t; e < 24 * 64; e += 256) {
    int hc = e >> 6, c = e & 63;
    float acc = 0.f;
    for (int co2 = 0; co2 < 128; ++co2) acc = fmaf(cent[hc][co2], wf[co2][c], acc);
    acc *= inv_l[hc];
    _Float16 hi = (_Float16)acc;
    _Float16 lo = (_Float16)(acc - (float)hi);
    int m = wc * 24 + hc;
    int mb = m >> 4, ccol = m & 15;
    int gq = (c >> 3) & 3, el = c & 7, jh = c >> 5;
    int lanei = ccol | (gq << 4);
    size_t base = (((size_t)bf * 36 + mb) * 4) * 512 + (size_t)lanei * 8 + el;
    cenW[base + (size_t)jh * 512] = hi;
    cenW[base + (size_t)(jh + 2) * 512] = lo;
  }
  if (bf == 0 && wc == 0) {
    for (int i = t; i < 128 * 64; i += 256) w_v_h[i] = (_Float16)w_v[i];
  }
  if (bf == 1) {
    for (int i = wc * 3072 + t; i < wc * 3072 + 3072; i += 256) {
      int co = i / 576, r = i % 576, dd = r >> 6, c = r & 63;
      w_skip_h[i] = (_Float16)w_skip[((co * 64 + c) * 3 + dd / 3) * 3 + (dd % 3)];
    }
  }
}

// ---------------------------------------------------------------------------
// K2: per (bf, tile of 128 points):
//   x staged as f32 xs[128][65]. Wave wid owns n-block half (wid&1, 4
//   n-blocks, B hi/lo fragments register-resident) and mb half (wid>>1,
//   18 iters). A loaded coalesced from fragment-major cenW with 1-deep
//   ping-pong prefetch; dvec folded into MFMA C-init. Two mb-halves merged
//   via LDS (lexicographic, bit-identical to full sweep). Segment-sum by
//   ownership gather; rare outliers via compact list. XCD-affinity swizzle.
// ---------------------------------------------------------------------------
__global__ __launch_bounds__(256, 3) void k2_assign(
    const float* __restrict__ x,
    const _Float16* __restrict__ cenW,
    const float* __restrict__ dvec,
    float* __restrict__ xsum, float* __restrict__ counts)
{
  const int id = blockIdx.x;          // 0..1151
  const int xcd = id & 7;
  const int j = id >> 3;              // 0..143
  const int bf = xcd * 8 + j / 18;
  const int tile = j % 18;
  const int b = bf >> 2, f1 = (bf >> 1) & 1, f2 = bf & 1;
  const int t = threadIdx.x;
  const int lane = t & 63, wid = t >> 6;

  const int tr = tile / 3, tc = tile % 3;
  const int w0 = tr * 8, h0 = tc * 16;

  __shared__ float xs[128][65];
  __shared__ float wbv[4][64];
  __shared__ int   wbi[4][64];
  __shared__ int   idxf[128];
  __shared__ int   olist[128];
  __shared__ int   ocnt;

  if (t == 0) ocnt = 0;

  for (int i = t; i < 64 * 128; i += 256) {
    int c = i >> 7, jj = i & 127;
    xs[jj][c] = x[((size_t)(b * 64 + c) * 96 + (f1 * 48 + w0 + (jj >> 4))) * 96
                  + f2 * 48 + h0 + (jj & 15)];
  }
  __syncthreads();

  const int ccol = lane & 15;
  const int g = lane >> 4;
  const int half = wid >> 1;          // mb half (0: 0..17, 1: 18..35)
  const int nbh = wid & 1;            // n-block half (0: n<64, 1: n>=64)

  // B fragments for 4 n-blocks, hi/lo split in VALU (register-resident)
  f16x8 Bh0[4], Bh1[4], Bl0[4], Bl1[4];
  #pragma unroll
  for (int q = 0; q < 4; ++q) {
    const int p = (nbh * 4 + q) * 16 + ccol;
    f16x8 h0v, h1v, l0v, l1v;
    #pragma unroll
    for (int e = 0; e < 8; ++e) {
      float v0 = xs[p][g * 8 + e];
      _Float16 hi0 = (_Float16)v0;
      h0v[e] = hi0; l0v[e] = (_Float16)(v0 - (float)hi0);
      float v1 = xs[p][32 + g * 8 + e];
      _Float16 hi1 = (_Float16)v1;
      h1v[e] = hi1; l1v[e] = (_Float16)(v1 - (float)hi1);
    }
    Bh0[q] = h0v; Bh1[q] = h1v; Bl0[q] = l0v; Bl1[q] = l1v;
  }

  const int mb0 = half * 18;
  const _Float16* abase = cenW + (size_t)bf * 73728 + (size_t)mb0 * 2048
                        + (size_t)lane * 8;
  const float* dv_bf = dvec + bf * 576 + g * 4;

  float bv[4];
  int bi[4];
  #pragma unroll
  for (int q = 0; q < 4; ++q) { bv[q] = -3.0e38f; bi[q] = 0; }

  f16x8 aA0 = *(const f16x8*)(abase);
  f16x8 aA1 = *(const f16x8*)(abase + 512);
  f16x8 aA2 = *(const f16x8*)(abase + 1024);
  f16x8 aA3 = *(const f16x8*)(abase + 1536);
  f16x8 aB0, aB1, aB2, aB3;

#define K2_BODY(kk, A0, A1, A2, A3)                                          \
  {                                                                          \
    const int mb = mb0 + (kk);                                               \
    f32x4 dv4 = *(const f32x4*)(dv_bf + mb * 16);                            \
    _Pragma("unroll")                                                        \
    for (int q = 0; q < 4; ++q) {                                            \
      f32x4 p4 = dv4;                                                        \
      f32x4 q4 = {0.f, 0.f, 0.f, 0.f};                                       \
      p4 = __builtin_amdgcn_mfma_f32_16x16x32_f16(A0, Bh0[q], p4, 0, 0, 0);  \
      q4 = __builtin_amdgcn_mfma_f32_16x16x32_f16(A1, Bh1[q], q4, 0, 0, 0);  \
      p4 = __builtin_amdgcn_mfma_f32_16x16x32_f16(A0, Bl0[q], p4, 0, 0, 0);  \
      q4 = __builtin_amdgcn_mfma_f32_16x16x32_f16(A1, Bl1[q], q4, 0, 0, 0);  \
      p4 = __builtin_amdgcn_mfma_f32_16x16x32_f16(A2, Bh0[q], p4, 0, 0, 0);  \
      q4 = __builtin_amdgcn_mfma_f32_16x16x32_f16(A3, Bh1[q], q4, 0, 0, 0);  \
      f32x4 v4 = p4 + q4;                                                    \
      _Pragma("unroll")                                                      \
      for (int r = 0; r < 4; ++r) {                                          \
        int m = mb * 16 + g * 4 + r;                                         \
        float vv = v4[r];                                                    \
        if (vv > bv[q] || (vv == bv[q] && m < bi[q])) { bv[q] = vv; bi[q] = m; } \
      }                                                                      \
    }                                                                        \
  }

  #pragma unroll 1
  for (int k = 0; k < 18; k += 2) {
    const _Float16* nb1 = abase + (size_t)(k + 1) * 2048;
    aB0 = *(const f16x8*)(nb1);
    aB1 = *(const f16x8*)(nb1 + 512);
    aB2 = *(const f16x8*)(nb1 + 1024);
    aB3 = *(const f16x8*)(nb1 + 1536);
    K2_BODY(k, aA0, aA1, aA2, aA3);
    const int kn = (k + 2 < 18) ? (k + 2) : 0;   // harmless reload on tail
    const _Float16* nb2 = abase + (size_t)kn * 2048;
    aA0 = *(const f16x8*)(nb2);
    aA1 = *(const f16x8*)(nb2 + 512);
    aA2 = *(const f16x8*)(nb2 + 1024);
    aA3 = *(const f16x8*)(nb2 + 1536);
    K2_BODY(k + 1, aB0, aB1, aB2, aB3);
  }
#undef K2_BODY

  // cross-g reduce within wave, then cross mb-half merge via LDS
  #pragma unroll
  for (int q = 0; q < 4; ++q) {
    float v = bv[q]; int mi = bi[q];
    #pragma unroll
    for (int off = 16; off <= 32; off <<= 1) {
      float ov = __shfl_xor(v, off, 64);
      int   oi = __shfl_xor(mi, off, 64);
      if (ov > v || (ov == v && oi < mi)) { v = ov; mi = oi; }
    }
    if (lane < 16) { wbv[wid][q * 16 + lane] = v; wbi[wid][q * 16 + lane] = mi; }
  }
  __syncthreads();

  if (t < 128) {
    int nbg = t >> 6;                 // which wave pair {nbg, nbg+2}
    int s = t & 63;
    float v0 = wbv[nbg][s];     int i0 = wbi[nbg][s];
    float v1 = wbv[nbg + 2][s]; int i1 = wbi[nbg + 2][s];
    int mi = (v1 > v0 || (v1 == v0 && i1 < i0)) ? i1 : i0;
    idxf[t] = mi;
    int own = (tr * 4 + ((t >> 4) >> 1)) * 24 + tc * 8 + ((t & 15) >> 1);
    if (mi != own) { int o = atomicAdd(&ocnt, 1); olist[o] = t; }
  }
  __syncthreads();

  // ownership gather: wave handles 8 interior centers, lanes = 64 channels
  for (int si = 0; si < 8; ++si) {
    const int s = wid * 8 + si;
    const int r = s >> 3, q = s & 7;
    const int m = (tr * 4 + r) * 24 + tc * 8 + q;
    const int p00 = (2 * r) * 16 + 2 * q;
    float sum = 0.f;
    int cnt = 0;
    #pragma unroll
    for (int dp = 0; dp < 4; ++dp) {
      const int p = p00 + (dp >> 1) * 16 + (dp & 1);
      if (idxf[p] == m) { sum += xs[p][lane]; ++cnt; }
    }
    if (cnt > 0) {
      atomicAdd(&xsum[((size_t)bf * 576 + m) * 64 + lane], sum);
      if (lane == 0) atomicAdd(&counts[bf * 576 + m], (float)cnt);
    }
  }

  // outliers (rare): wave per outlier point, lanes = channels
  for (int o = wid; o < ocnt; o += 4) {
    const int p = olist[o];
    const int m = idxf[p];
    atomicAdd(&xsum[((size_t)bf * 576 + m) * 64 + lane], xs[p][lane]);
    if (lane == 0) atomicAdd(&counts[bf * 576 + m], 1.0f);
  }
}

// ---------------------------------------------------------------------------
// K2c: pooled GEMM + divide + GroupNorm stats:
//   om[m][co] = (W_v·(xsum[m]+xc[m]))/(cnt[m]+1) + b_v[co]   (f16 out)
//   gn_sum/gn_ss += per-b partial sums of om.
// ---------------------------------------------------------------------------
__global__ __launch_bounds__(256) void k2c_pool(
    const float* __restrict__ xsum, const float* __restrict__ xc,
    const float* __restrict__ counts, const _Float16* __restrict__ w_v_h,
    const float* __restrict__ b_v, _Float16* __restrict__ om,
    float* __restrict__ gn_sum, float* __restrict__ gn_ss)
{
  const int chunk = blockIdx.x;       // 0..3
  const int bf = blockIdx.y;          // 0..63
  const int m0 = chunk * 144;
  const int t = threadIdx.x;
  const int lane = t & 63, wid = t >> 6;

  __shared__ __align__(16) _Float16 bh[144][72];
  __shared__ __align__(16) _Float16 bl[144][72];
  __shared__ float rcp_l[144];

  for (int i = t; i < 144 * 64; i += 256) {
    int mq = i >> 6, c = i & 63;
    size_t gdx = ((size_t)bf * 576 + m0 + mq) * 64 + c;
    float s = xsum[gdx] + xc[gdx];
    _Float16 hi = (_Float16)s;
    bh[mq][c] = hi;
    bl[mq][c] = (_Float16)(s - (float)hi);
  }
  if (t < 144) rcp_l[t] = 1.0f / (counts[bf * 576 + m0 + t] + 1.0f);
  __syncthreads();

  const int ccol = lane & 15, row0 = (lane >> 4) * 4, c0 = (lane >> 4) * 8;
  float sacc = 0.f, ssacc = 0.f;

  #pragma unroll
  for (int cbi = 0; cbi < 2; ++cbi) {
    const int cb = wid + cbi * 4;
    const size_t abase = (size_t)(cb * 16 + ccol) * 64;
    f16x8 a0 = *(const f16x8*)(w_v_h + abase + c0);
    f16x8 a1 = *(const f16x8*)(w_v_h + abase + 32 + c0);
    float bvv[4];
    #pragma unroll
    for (int r = 0; r < 4; ++r) bvv[r] = b_v[cb * 16 + row0 + r];
    for (int nb = 0; nb < 9; ++nb) {
      int mq = nb * 16 + ccol;
      f16x8 bh0 = *(const f16x8*)(&bh[mq][c0]);
      f16x8 bh1 = *(const f16x8*)(&bh[mq][32 + c0]);
      f16x8 bl0 = *(const f16x8*)(&bl[mq][c0]);
      f16x8 bl1 = *(const f16x8*)(&bl[mq][32 + c0]);
      f32x4 a2 = {0.f, 0.f, 0.f, 0.f};
      a2 = __builtin_amdgcn_mfma_f32_16x16x32_f16(a0, bh0, a2, 0, 0, 0);
      a2 = __builtin_amdgcn_mfma_f32_16x16x32_f16(a1, bh1, a2, 0, 0, 0);
      a2 = __builtin_amdgcn_mfma_f32_16x16x32_f16(a0, bl0, a2, 0, 0, 0);
      a2 = __builtin_amdgcn_mfma_f32_16x16x32_f16(a1, bl1, a2, 0, 0, 0);
      float rcp = rcp_l[mq];
      f16x4 o4;
      #pragma unroll
      for (int r = 0; r < 4; ++r) {
        float ov = a2[r] * rcp + bvv[r];
        sacc += ov; ssacc += ov * ov;
        o4[r] = (_Float16)ov;
      }
      *(f16x4*)(om + ((size_t)bf * 576 + m0 + mq) * 128 + cb * 16 + row0) = o4;
    }
  }

  #pragma unroll
  for (int off = 1; off < 64; off <<= 1) {
    sacc += __shfl_xor(sacc, off, 64);
    ssacc += __shfl_xor(ssacc, off, 64);
  }
  __shared__ float rs[4], rss[4];
  if (lane == 0) { rs[wid] = sacc; rss[wid] = ssacc; }
  __syncthreads();
  if (t == 0) {
    atomicAdd(gn_sum + (bf >> 2), rs[0] + rs[1] + rs[2] + rs[3]);
    atomicAdd(gn_ss + (bf >> 2), rss[0] + rss[1] + rss[2] + rss[3]);
  }
}

// ---------------------------------------------------------------------------
// K4: per (b, output row o2): skip conv via implicit-GEMM f16 MFMA (K=576)
//     + GroupNorm apply + unfold + add.
// ---------------------------------------------------------------------------
__global__ __launch_bounds__(256) void k4_final(
    const float* __restrict__ x, const _Float16* __restrict__ w_skip_h,
    const float* __restrict__ b_skip, const _Float16* __restrict__ om,
    const float* __restrict__ gn_sum, const float* __restrict__ gn_ss,
    const float* __restrict__ gamma, const float* __restrict__ beta,
    float* __restrict__ out)
{
  const int o2 = blockIdx.x;          // 0..47
  const int b = blockIdx.y;           // 0..15
  const int t = threadIdx.x;
  const int lane = t & 63, wid = t >> 6;

  __shared__ __align__(16) _Float16 xcol[3][2][49][72];
  __shared__ _Float16 raw[64][3][98];

  for (int i = t; i < 64 * 3 * 96; i += 256) {
    int c = i / 288, r = i % 288, dh = r / 96, col = r % 96;
    int R = 2 * o2 + dh - 1;
    float v = (R >= 0) ? x[((size_t)(b * 64 + c) * 96 + R) * 96 + col] : 0.f;
    raw[c][dh][col] = (_Float16)v;
  }
  __syncthreads();
  for (int i = t; i < 3 * 98 * 64; i += 256) {
    int c = i & 63, r = i >> 6, cc = r % 98, dh = r / 98;
    _Float16 v = (_Float16)0.f;
    if (cc >= 1 && cc <= 96) v = raw[c][dh][cc - 1];
    xcol[dh][cc & 1][cc >> 1][c] = v;
  }
  __syncthreads();

  const float Ninv = 1.0f / 294912.0f;
  const float mu = gn_sum[b] * Ninv;
  const float var = gn_ss[b] * Ninv - mu * mu;
  const float istd = rsqrtf(var + 1e-5f);
  const int f1 = o2 / 24, w24 = o2 % 24;

  const int ccol = lane & 15, row0 = (lane >> 4) * 4, c0 = (lane >> 4) * 8;

  for (int tt = wid * 6; tt < wid * 6 + 6; ++tt) {
    int mb = tt / 3, nb = tt % 3;
    f32x4 a2 = {0.f, 0.f, 0.f, 0.f};
    const _Float16* wrow = w_skip_h + (size_t)(mb * 16 + ccol) * 576;
    const int o3 = nb * 16 + ccol;
    #pragma unroll
    for (int ks = 0; ks < 18; ++ks) {
      int dd = ks >> 1;
      int dh = dd / 3, dw = dd % 3;
      int cl = (ks & 1) * 32 + c0;
      f16x8 a = *(const f16x8*)(wrow + ks * 32 + c0);
      f16x8 bb = *(const f16x8*)(&xcol[dh][dw & 1][o3 + (dw >> 1)][cl]);
      a2 = __builtin_amdgcn_mfma_f32_16x16x32_f16(a, bb, a2, 0, 0, 0);
    }
    const int f2 = o3 / 24, h = o3 % 24;
    const int bf = ((b * 2 + f1) * 2) + f2;
    const int m = w24 * 24 + h;
    #pragma unroll
    for (int r = 0; r < 4; ++r) {
      int co = mb * 16 + row0 + r;
      float om_v = (float)om[((size_t)bf * 576 + m) * 128 + co];
      float gnv = (om_v - mu) * istd * gamma[co] + beta[co];
      out[((size_t)(b * 128 + co) * 48 + o2) * 48 + o3] = a2[r] + b_skip[co] + gnv;
    }
  }
}

// ---------------------------------------------------------------------------
extern "C" void kernel_launch(void* const* d_in, const int* in_sizes, int n_in,
                              void* d_out, int out_size, void* d_ws, size_t ws_size,
                              hipStream_t stream) {
  const float* x      = (const float*)d_in[0];
  const float* w_f    = (const float*)d_in[1];
  const float* b_f    = (const float*)d_in[2];
  const float* w_v    = (const float*)d_in[3];
  const float* b_v    = (const float*)d_in[4];
  const float* w_skip = (const float*)d_in[5];
  const float* b_skip = (const float*)d_in[6];
  const float* gamma  = (const float*)d_in[7];
  const float* beta   = (const float*)d_in[8];
  float* out = (float*)d_out;

  char* ws = (char*)d_ws;
  _Float16* cenW     = (_Float16*)(ws);                 // 9,437,184 (frag-major hi+lo)
  _Float16* om       = (_Float16*)(ws);                 // aliases cenW (dead after K2)
  float*    dvec     = (float*)(ws + 9437184);          // 147,456
  float*    xc       = (float*)(ws + 9584640);          // 9,437,184
  _Float16* w_v_h    = (_Float16*)(ws + 19021824);      // 16,384
  _Float16* w_skip_h = (_Float16*)(ws + 19038208);      // 147,456
  float*    xsum     = (float*)(ws + 19185664);         // 9,437,184  [memset]
  float*    counts   = (float*)(ws + 28622848);         // 147,456    [memset]
  float*    gn_sum   = (float*)(ws + 28770304);         // 256        [memset]
  float*    gn_ss    = (float*)(ws + 28770560);         // 256        [memset]

  hipMemsetAsync(ws + 19185664, 0, 9585152, stream);

  k1_centers<<<dim3(24, 64), dim3(256), 0, stream>>>(
      x, w_f, b_f, w_v, w_skip, cenW, dvec, xc, w_v_h, w_skip_h);
  k2_assign<<<dim3(1152), dim3(256), 0, stream>>>(
      x, cenW, dvec, xsum, counts);
  k2c_pool<<<dim3(4, 64), dim3(256), 0, stream>>>(
      xsum, xc, counts, w_v_h, b_v, om, gn_sum, gn_ss);
  k4_final<<<dim3(48, 16), dim3(256), 0, stream>>>(
      x, w_skip_h, b_skip, om, gn_sum, gn_ss, gamma, beta, out);
}

// Round 6
// 179.710 us; speedup vs baseline: 4.0950x; 1.4291x over previous
//
#include <hip/hip_runtime.h>

typedef _Float16 f16x8 __attribute__((ext_vector_type(8)));
typedef _Float16 f16x4 __attribute__((ext_vector_type(4)));
typedef float f32x4 __attribute__((ext_vector_type(4)));

// ---------------------------------------------------------------------------
// K1: per (bf quadrant, wc row of 24 centers):
//   xc = 2x2-avgpool(x)  -> written directly into xsum (segment-sum init)
//   centers = W_f xc + b_f;  cen = centers/||centers||
//   cenW[m][cin] = W_f^T cen[m], fragment-major f16 hi/lo: [bf][mb][j][lane][8]
//   d[m] = cen[m]·b_f
//   side jobs: xt16[b][h][w][c] f16 transpose of x (this block's 2x48 patch),
//              w_v -> f16, w_skip -> fragment-major wsf[mb][ks][lane][8]
// ---------------------------------------------------------------------------
__global__ __launch_bounds__(256) void k1_centers(
    const float* __restrict__ x, const float* __restrict__ w_f,
    const float* __restrict__ b_f, const float* __restrict__ w_v,
    const float* __restrict__ w_skip,
    _Float16* __restrict__ cenW,
    float* __restrict__ dvec, float* __restrict__ xsum,
    _Float16* __restrict__ w_v_h, _Float16* __restrict__ wsf,
    _Float16* __restrict__ xt16)
{
  const int wc = blockIdx.x;          // 0..23
  const int bf = blockIdx.y;          // 0..63
  const int b = bf >> 2, f1 = (bf >> 1) & 1, f2 = bf & 1;
  const int t = threadIdx.x;

  __shared__ float wf[128][65];
  __shared__ float xc[24][65];
  __shared__ float cent[24][130];
  __shared__ float inv_l[24];

  for (int i = t; i < 128 * 64; i += 256) {
    int co = i >> 6, c = i & 63;
    wf[co][c] = w_f[i];
  }
  for (int e = t; e < 64 * 24; e += 256) {
    int c = e / 24, hc = e % 24;
    const int R0 = f1 * 48 + 2 * wc, C0 = f2 * 48 + 2 * hc;
    const float* xp = x + ((size_t)(b * 64 + c) * 96 + R0) * 96 + C0;
    float v0 = xp[0], v1 = xp[1], v2 = xp[96], v3 = xp[97];
    xc[hc][c] = 0.25f * (v0 + v1 + v2 + v3);
    // xt16 transpose side-job (each x element touched exactly once globally)
    _Float16* xo = xt16 + (((size_t)b * 96 + R0) * 96 + C0) * 64 + c;
    xo[0] = (_Float16)v0;
    xo[64] = (_Float16)v1;
    xo[96 * 64] = (_Float16)v2;
    xo[97 * 64] = (_Float16)v3;
  }
  __syncthreads();
  {
    const int co = t & 127;
    const int hg = t >> 7;
    for (int p = 0; p < 12; ++p) {
      int hc = p * 2 + hg;
      float accf = b_f[co];
      #pragma unroll
      for (int c = 0; c < 64; ++c) accf = fmaf(wf[co][c], xc[hc][c], accf);
      cent[hc][co] = accf;
    }
  }
  for (int e = t; e < 24 * 64; e += 256) {
    int hc = e >> 6, c = e & 63;
    xsum[((size_t)bf * 576 + wc * 24 + hc) * 64 + c] = xc[hc][c];
  }
  __syncthreads();
  if (t < 24) {
    float ss = 0.f, db = 0.f;
    for (int c = 0; c < 128; ++c) { float v = cent[t][c]; ss += v * v; db += v * b_f[c]; }
    float inv = 1.0f / fmaxf(sqrtf(ss), 1e-12f);
    inv_l[t] = inv;
    dvec[bf * 576 + wc * 24 + t] = inv * db;
  }
  __syncthreads();
  for (int e = t; e < 24 * 64; e += 256) {
    int hc = e >> 6, c = e & 63;
    float acc = 0.f;
    for (int co2 = 0; co2 < 128; ++co2) acc = fmaf(cent[hc][co2], wf[co2][c], acc);
    acc *= inv_l[hc];
    _Float16 hi = (_Float16)acc;
    _Float16 lo = (_Float16)(acc - (float)hi);
    int m = wc * 24 + hc;
    int mb = m >> 4, ccol = m & 15;
    int gq = (c >> 3) & 3, el = c & 7, jh = c >> 5;
    int lanei = ccol | (gq << 4);
    size_t base = (((size_t)bf * 36 + mb) * 4) * 512 + (size_t)lanei * 8 + el;
    cenW[base + (size_t)jh * 512] = hi;
    cenW[base + (size_t)(jh + 2) * 512] = lo;
  }
  if (bf == 0 && wc == 0) {
    for (int i = t; i < 128 * 64; i += 256) w_v_h[i] = (_Float16)w_v[i];
  }
  if (bf == 1) {
    // wsf[mb][ks][lane=(ccol|g<<4)][e] <- w_skip f16, k = ks*32+g*8+e
    for (int i = wc * 3072 + t; i < wc * 3072 + 3072; i += 256) {
      int co = i / 576, kk = i % 576;
      int dd = kk >> 6, c = kk & 63, dh = dd / 3, dw = dd % 3;
      int mb = co >> 4, ccol = co & 15;
      int ks = kk >> 5, g = (kk >> 3) & 3, e = kk & 7;
      size_t dst = (((size_t)mb * 18 + ks) * 64 + (ccol | (g << 4))) * 8 + e;
      wsf[dst] = (_Float16)w_skip[((co * 64 + c) * 3 + dh) * 3 + dw];
    }
  }
}

// ---------------------------------------------------------------------------
// K2: per (bf, tile of 128 points): argmax via 3-term split f16 MFMA with
//   register-resident B, fragment-major A stream, mb-split across wave pairs;
//   segment-sum into xsum (pre-initialized with avgpool) by ownership gather.
// ---------------------------------------------------------------------------
__global__ __launch_bounds__(256, 3) void k2_assign(
    const float* __restrict__ x,
    const _Float16* __restrict__ cenW,
    const float* __restrict__ dvec,
    float* __restrict__ xsum, float* __restrict__ counts)
{
  const int id = blockIdx.x;          // 0..1151
  const int xcd = id & 7;
  const int j = id >> 3;              // 0..143
  const int bf = xcd * 8 + j / 18;
  const int tile = j % 18;
  const int b = bf >> 2, f1 = (bf >> 1) & 1, f2 = bf & 1;
  const int t = threadIdx.x;
  const int lane = t & 63, wid = t >> 6;

  const int tr = tile / 3, tc = tile % 3;
  const int w0 = tr * 8, h0 = tc * 16;

  __shared__ float xs[128][65];
  __shared__ float wbv[4][64];
  __shared__ int   wbi[4][64];
  __shared__ int   idxf[128];
  __shared__ int   olist[128];
  __shared__ int   ocnt;

  if (t == 0) ocnt = 0;

  for (int i = t; i < 64 * 128; i += 256) {
    int c = i >> 7, jj = i & 127;
    xs[jj][c] = x[((size_t)(b * 64 + c) * 96 + (f1 * 48 + w0 + (jj >> 4))) * 96
                  + f2 * 48 + h0 + (jj & 15)];
  }
  __syncthreads();

  const int ccol = lane & 15;
  const int g = lane >> 4;
  const int half = wid >> 1;          // mb half (0: 0..17, 1: 18..35)
  const int nbh = wid & 1;            // n-block half (0: n<64, 1: n>=64)

  f16x8 Bh0[4], Bh1[4], Bl0[4], Bl1[4];
  #pragma unroll
  for (int q = 0; q < 4; ++q) {
    const int p = (nbh * 4 + q) * 16 + ccol;
    f16x8 h0v, h1v, l0v, l1v;
    #pragma unroll
    for (int e = 0; e < 8; ++e) {
      float v0 = xs[p][g * 8 + e];
      _Float16 hi0 = (_Float16)v0;
      h0v[e] = hi0; l0v[e] = (_Float16)(v0 - (float)hi0);
      float v1 = xs[p][32 + g * 8 + e];
      _Float16 hi1 = (_Float16)v1;
      h1v[e] = hi1; l1v[e] = (_Float16)(v1 - (float)hi1);
    }
    Bh0[q] = h0v; Bh1[q] = h1v; Bl0[q] = l0v; Bl1[q] = l1v;
  }

  const int mb0 = half * 18;
  const _Float16* abase = cenW + (size_t)bf * 73728 + (size_t)mb0 * 2048
                        + (size_t)lane * 8;
  const float* dv_bf = dvec + bf * 576 + g * 4;

  float bv[4];
  int bi[4];
  #pragma unroll
  for (int q = 0; q < 4; ++q) { bv[q] = -3.0e38f; bi[q] = 0; }

  f16x8 aA0 = *(const f16x8*)(abase);
  f16x8 aA1 = *(const f16x8*)(abase + 512);
  f16x8 aA2 = *(const f16x8*)(abase + 1024);
  f16x8 aA3 = *(const f16x8*)(abase + 1536);
  f16x8 aB0, aB1, aB2, aB3;

#define K2_BODY(kk, A0, A1, A2, A3)                                          \
  {                                                                          \
    const int mb = mb0 + (kk);                                               \
    f32x4 dv4 = *(const f32x4*)(dv_bf + mb * 16);                            \
    _Pragma("unroll")                                                        \
    for (int q = 0; q < 4; ++q) {                                            \
      f32x4 p4 = dv4;                                                        \
      f32x4 q4 = {0.f, 0.f, 0.f, 0.f};                                       \
      p4 = __builtin_amdgcn_mfma_f32_16x16x32_f16(A0, Bh0[q], p4, 0, 0, 0);  \
      q4 = __builtin_amdgcn_mfma_f32_16x16x32_f16(A1, Bh1[q], q4, 0, 0, 0);  \
      p4 = __builtin_amdgcn_mfma_f32_16x16x32_f16(A0, Bl0[q], p4, 0, 0, 0);  \
      q4 = __builtin_amdgcn_mfma_f32_16x16x32_f16(A1, Bl1[q], q4, 0, 0, 0);  \
      p4 = __builtin_amdgcn_mfma_f32_16x16x32_f16(A2, Bh0[q], p4, 0, 0, 0);  \
      q4 = __builtin_amdgcn_mfma_f32_16x16x32_f16(A3, Bh1[q], q4, 0, 0, 0);  \
      f32x4 v4 = p4 + q4;                                                    \
      _Pragma("unroll")                                                      \
      for (int r = 0; r < 4; ++r) {                                          \
        int m = mb * 16 + g * 4 + r;                                         \
        float vv = v4[r];                                                    \
        if (vv > bv[q] || (vv == bv[q] && m < bi[q])) { bv[q] = vv; bi[q] = m; } \
      }                                                                      \
    }                                                                        \
  }

  #pragma unroll 1
  for (int k = 0; k < 18; k += 2) {
    const _Float16* nb1 = abase + (size_t)(k + 1) * 2048;
    aB0 = *(const f16x8*)(nb1);
    aB1 = *(const f16x8*)(nb1 + 512);
    aB2 = *(const f16x8*)(nb1 + 1024);
    aB3 = *(const f16x8*)(nb1 + 1536);
    K2_BODY(k, aA0, aA1, aA2, aA3);
    const int kn = (k + 2 < 18) ? (k + 2) : 0;
    const _Float16* nb2 = abase + (size_t)kn * 2048;
    aA0 = *(const f16x8*)(nb2);
    aA1 = *(const f16x8*)(nb2 + 512);
    aA2 = *(const f16x8*)(nb2 + 1024);
    aA3 = *(const f16x8*)(nb2 + 1536);
    K2_BODY(k + 1, aB0, aB1, aB2, aB3);
  }
#undef K2_BODY

  #pragma unroll
  for (int q = 0; q < 4; ++q) {
    float v = bv[q]; int mi = bi[q];
    #pragma unroll
    for (int off = 16; off <= 32; off <<= 1) {
      float ov = __shfl_xor(v, off, 64);
      int   oi = __shfl_xor(mi, off, 64);
      if (ov > v || (ov == v && oi < mi)) { v = ov; mi = oi; }
    }
    if (lane < 16) { wbv[wid][q * 16 + lane] = v; wbi[wid][q * 16 + lane] = mi; }
  }
  __syncthreads();

  if (t < 128) {
    int nbg = t >> 6;
    int s = t & 63;
    float v0 = wbv[nbg][s];     int i0 = wbi[nbg][s];
    float v1 = wbv[nbg + 2][s]; int i1 = wbi[nbg + 2][s];
    int mi = (v1 > v0 || (v1 == v0 && i1 < i0)) ? i1 : i0;
    idxf[t] = mi;
    int own = (tr * 4 + ((t >> 4) >> 1)) * 24 + tc * 8 + ((t & 15) >> 1);
    if (mi != own) { int o = atomicAdd(&ocnt, 1); olist[o] = t; }
  }
  __syncthreads();

  for (int si = 0; si < 8; ++si) {
    const int s = wid * 8 + si;
    const int r = s >> 3, q = s & 7;
    const int m = (tr * 4 + r) * 24 + tc * 8 + q;
    const int p00 = (2 * r) * 16 + 2 * q;
    float sum = 0.f;
    int cnt = 0;
    #pragma unroll
    for (int dp = 0; dp < 4; ++dp) {
      const int p = p00 + (dp >> 1) * 16 + (dp & 1);
      if (idxf[p] == m) { sum += xs[p][lane]; ++cnt; }
    }
    if (cnt > 0) {
      atomicAdd(&xsum[((size_t)bf * 576 + m) * 64 + lane], sum);
      if (lane == 0) atomicAdd(&counts[bf * 576 + m], (float)cnt);
    }
  }

  for (int o = wid; o < ocnt; o += 4) {
    const int p = olist[o];
    const int m = idxf[p];
    atomicAdd(&xsum[((size_t)bf * 576 + m) * 64 + lane], xs[p][lane]);
    if (lane == 0) atomicAdd(&counts[bf * 576 + m], 1.0f);
  }
}

// ---------------------------------------------------------------------------
// K2c: pooled GEMM + divide + GroupNorm stats:
//   om[m][co] = (W_v·xsum[m])/(cnt[m]+1) + b_v[co]   (f16 out)
// ---------------------------------------------------------------------------
__global__ __launch_bounds__(256) void k2c_pool(
    const float* __restrict__ xsum,
    const float* __restrict__ counts, const _Float16* __restrict__ w_v_h,
    const float* __restrict__ b_v, _Float16* __restrict__ om,
    float* __restrict__ gn_sum, float* __restrict__ gn_ss)
{
  const int chunk = blockIdx.x;       // 0..3
  const int bf = blockIdx.y;          // 0..63
  const int m0 = chunk * 144;
  const int t = threadIdx.x;
  const int lane = t & 63, wid = t >> 6;

  __shared__ __align__(16) _Float16 bh[144][72];
  __shared__ __align__(16) _Float16 bl[144][72];
  __shared__ float rcp_l[144];

  for (int i = t; i < 144 * 64; i += 256) {
    int mq = i >> 6, c = i & 63;
    size_t gdx = ((size_t)bf * 576 + m0 + mq) * 64 + c;
    float s = xsum[gdx];
    _Float16 hi = (_Float16)s;
    bh[mq][c] = hi;
    bl[mq][c] = (_Float16)(s - (float)hi);
  }
  if (t < 144) rcp_l[t] = 1.0f / (counts[bf * 576 + m0 + t] + 1.0f);
  __syncthreads();

  const int ccol = lane & 15, row0 = (lane >> 4) * 4, c0 = (lane >> 4) * 8;
  float sacc = 0.f, ssacc = 0.f;

  #pragma unroll
  for (int cbi = 0; cbi < 2; ++cbi) {
    const int cb = wid + cbi * 4;
    const size_t abase = (size_t)(cb * 16 + ccol) * 64;
    f16x8 a0 = *(const f16x8*)(w_v_h + abase + c0);
    f16x8 a1 = *(const f16x8*)(w_v_h + abase + 32 + c0);
    float bvv[4];
    #pragma unroll
    for (int r = 0; r < 4; ++r) bvv[r] = b_v[cb * 16 + row0 + r];
    for (int nb = 0; nb < 9; ++nb) {
      int mq = nb * 16 + ccol;
      f16x8 bh0 = *(const f16x8*)(&bh[mq][c0]);
      f16x8 bh1 = *(const f16x8*)(&bh[mq][32 + c0]);
      f16x8 bl0 = *(const f16x8*)(&bl[mq][c0]);
      f16x8 bl1 = *(const f16x8*)(&bl[mq][32 + c0]);
      f32x4 a2 = {0.f, 0.f, 0.f, 0.f};
      a2 = __builtin_amdgcn_mfma_f32_16x16x32_f16(a0, bh0, a2, 0, 0, 0);
      a2 = __builtin_amdgcn_mfma_f32_16x16x32_f16(a1, bh1, a2, 0, 0, 0);
      a2 = __builtin_amdgcn_mfma_f32_16x16x32_f16(a0, bl0, a2, 0, 0, 0);
      a2 = __builtin_amdgcn_mfma_f32_16x16x32_f16(a1, bl1, a2, 0, 0, 0);
      float rcp = rcp_l[mq];
      f16x4 o4;
      #pragma unroll
      for (int r = 0; r < 4; ++r) {
        float ov = a2[r] * rcp + bvv[r];
        sacc += ov; ssacc += ov * ov;
        o4[r] = (_Float16)ov;
      }
      *(f16x4*)(om + ((size_t)bf * 576 + m0 + mq) * 128 + cb * 16 + row0) = o4;
    }
  }

  #pragma unroll
  for (int off = 1; off < 64; off <<= 1) {
    sacc += __shfl_xor(sacc, off, 64);
    ssacc += __shfl_xor(ssacc, off, 64);
  }
  __shared__ float rs[4], rss[4];
  if (lane == 0) { rs[wid] = sacc; rss[wid] = ssacc; }
  __syncthreads();
  if (t == 0) {
    atomicAdd(gn_sum + (bf >> 2), rs[0] + rs[1] + rs[2] + rs[3]);
    atomicAdd(gn_ss + (bf >> 2), rss[0] + rss[1] + rss[2] + rss[3]);
  }
}

// ---------------------------------------------------------------------------
// K4: per (b, output row o2): skip conv as implicit GEMM, A from
//   fragment-major wsf (coalesced L2 stream), B from xt16 staged in LDS with
//   XOR chunk-swizzle (conflict-free writes AND reads); register-chunked
//   K-loop (6 chunks x {6 A-loads, 9 ds_read_b128, 18 MFMA});
//   epilogue: GroupNorm apply + unfold + bias + add.  37 KB LDS -> 4 blk/CU.
// ---------------------------------------------------------------------------
__global__ __launch_bounds__(256, 4) void k4_final(
    const _Float16* __restrict__ xt16, const _Float16* __restrict__ wsf,
    const float* __restrict__ b_skip, const _Float16* __restrict__ om,
    const float* __restrict__ gn_sum, const float* __restrict__ gn_ss,
    const float* __restrict__ gamma, const float* __restrict__ beta,
    float* __restrict__ out)
{
  const int o2 = blockIdx.x;          // 0..47
  const int b  = blockIdx.y;          // 0..15
  const int t = threadIdx.x;
  const int lane = t & 63, wid = t >> 6;

  __shared__ __align__(16) _Float16 xl[3 * 97 * 64];  // [rr][colp][chunk-swizzled c]

  // zero the colp=0 (left-pad) column blocks
  if (t < 96) {
    int rr = t >> 5, h2 = t & 31;
    *(unsigned int*)&xl[(rr * 97) * 64 + h2 * 2] = 0u;
  }

  // stage 3 input rows (gr = 2*o2-1+rr) of xt16, chunk-swizzled
  for (int i = t; i < 2304; i += 256) {
    int rr = i / 768, rem = i % 768, col = rem >> 3, cg = rem & 7;
    int gr = 2 * o2 - 1 + rr;
    f16x8 v = {};
    if (gr >= 0)
      v = *(const f16x8*)(xt16 + (((size_t)b * 96 + gr) * 96 + col) * 64 + cg * 8);
    int colp = col + 1;
    *(f16x8*)&xl[(rr * 97 + colp) * 64 + ((cg ^ (colp & 7)) << 3)] = v;
  }
  __syncthreads();

  const int ccol = lane & 15, g = lane >> 4;
  const int mb0 = wid * 2;            // this wave's mb pair

  f32x4 acc[2][3] = {};
  const int o3a = ccol;               // o3 = nb*16 + ccol

  #pragma unroll 1
  for (int kc = 0; kc < 6; ++kc) {
    f16x8 A[2][3];
    #pragma unroll
    for (int m2 = 0; m2 < 2; ++m2)
      #pragma unroll
      for (int kq = 0; kq < 3; ++kq) {
        int ks = kc * 3 + kq;
        A[m2][kq] = *(const f16x8*)(wsf + (((size_t)(mb0 + m2) * 18 + ks) * 64 + lane) * 8);
      }
    #pragma unroll
    for (int nb = 0; nb < 3; ++nb) {
      const int o3 = nb * 16 + o3a;
      f16x8 Bf[3];
      #pragma unroll
      for (int kq = 0; kq < 3; ++kq) {
        int ks = kc * 3 + kq;
        int dd = ks >> 1, dh = dd / 3, dw = dd % 3, ch = ks & 1;
        int colp = 2 * o3 + dw;       // input col + 1
        Bf[kq] = *(const f16x8*)&xl[(dh * 97 + colp) * 64
                                    + ((((ch << 2) | g) ^ (colp & 7)) << 3)];
      }
      #pragma unroll
      for (int kq = 0; kq < 3; ++kq) {
        acc[0][nb] = __builtin_amdgcn_mfma_f32_16x16x32_f16(A[0][kq], Bf[kq], acc[0][nb], 0, 0, 0);
        acc[1][nb] = __builtin_amdgcn_mfma_f32_16x16x32_f16(A[1][kq], Bf[kq], acc[1][nb], 0, 0, 0);
      }
    }
  }

  const float Ninv = 1.0f / 294912.0f;
  const float mu = gn_sum[b] * Ninv;
  const float var = gn_ss[b] * Ninv - mu * mu;
  const float istd = rsqrtf(var + 1e-5f);
  const int f1 = o2 / 24, w24 = o2 % 24;

  #pragma unroll
  for (int m2 = 0; m2 < 2; ++m2) {
    const int mb = mb0 + m2;
    #pragma unroll
    for (int nb = 0; nb < 3; ++nb) {
      const int o3 = nb * 16 + o3a;
      const int f2 = o3 / 24, h = o3 % 24;
      const int bf = b * 4 + f1 * 2 + f2;
      const int m = w24 * 24 + h;
      f16x4 o4 = *(const f16x4*)(om + ((size_t)bf * 576 + m) * 128 + mb * 16 + g * 4);
      #pragma unroll
      for (int r = 0; r < 4; ++r) {
        int co = mb * 16 + g * 4 + r;
        float gnv = ((float)o4[r] - mu) * istd * gamma[co] + beta[co];
        out[((size_t)(b * 128 + co) * 48 + o2) * 48 + o3] = acc[m2][nb][r] + b_skip[co] + gnv;
      }
    }
  }
}

// ---------------------------------------------------------------------------
extern "C" void kernel_launch(void* const* d_in, const int* in_sizes, int n_in,
                              void* d_out, int out_size, void* d_ws, size_t ws_size,
                              hipStream_t stream) {
  const float* x      = (const float*)d_in[0];
  const float* w_f    = (const float*)d_in[1];
  const float* b_f    = (const float*)d_in[2];
  const float* w_v    = (const float*)d_in[3];
  const float* b_v    = (const float*)d_in[4];
  const float* w_skip = (const float*)d_in[5];
  const float* b_skip = (const float*)d_in[6];
  const float* gamma  = (const float*)d_in[7];
  const float* beta   = (const float*)d_in[8];
  float* out = (float*)d_out;

  char* ws = (char*)d_ws;
  _Float16* cenW   = (_Float16*)(ws);                 // 9,437,184 (frag-major hi+lo)
  _Float16* om     = (_Float16*)(ws);                 // aliases cenW (dead after K2)
  float*    dvec   = (float*)(ws + 9437184);          // 147,456
  _Float16* wsf    = (_Float16*)(ws + 9584640);       // 147,456 (frag-major w_skip)
  _Float16* w_v_h  = (_Float16*)(ws + 9732096);       // 16,384
  float*    xsum   = (float*)(ws + 9748480);          // 9,437,184 (init by K1)
  float*    counts = (float*)(ws + 19185664);         // 147,456   [memset]
  float*    gn_sum = (float*)(ws + 19333120);         // 256       [memset]
  float*    gn_ss  = (float*)(ws + 19333376);         // 256       [memset]
  _Float16* xt16   = (_Float16*)(ws + 19333632);      // 18,874,368 (x -> [b][h][w][c] f16)

  hipMemsetAsync(ws + 19185664, 0, 147968, stream);

  k1_centers<<<dim3(24, 64), dim3(256), 0, stream>>>(
      x, w_f, b_f, w_v, w_skip, cenW, dvec, xsum, w_v_h, wsf, xt16);
  k2_assign<<<dim3(1152), dim3(256), 0, stream>>>(
      x, cenW, dvec, xsum, counts);
  k2c_pool<<<dim3(4, 64), dim3(256), 0, stream>>>(
      xsum, counts, w_v_h, b_v, om, gn_sum, gn_ss);
  k4_final<<<dim3(48, 16), dim3(256), 0, stream>>>(
      xt16, wsf, b_skip, om, gn_sum, gn_ss, gamma, beta, out);
}

// Round 9
// 130.332 us; speedup vs baseline: 5.6465x; 1.3789x over previous
//
#include <hip/hip_runtime.h>

typedef _Float16 f16x8 __attribute__((ext_vector_type(8)));
typedef _Float16 f16x4 __attribute__((ext_vector_type(4)));
typedef float f32x4 __attribute__((ext_vector_type(4)));

// ---------------------------------------------------------------------------
// K1a: blocks 0..767 (b x row-pair): transpose x -> xt16 [b][h][w][c] f16 and
//      write 2x2 avgpool directly into xsum (segment-sum initializer).
//      blocks 768..783: weight prep: w_f -> wfA (GEMM1 A-frags, hi/lo) and
//      wfT (GEMM2 B-frags, hi/lo); w_v -> f16; w_skip -> fragment-major wsf
//      (full 73,728 elements: 16 blocks x 4608).
// ---------------------------------------------------------------------------
__global__ __launch_bounds__(256) void k1a_prep(
    const float* __restrict__ x, const float* __restrict__ w_f,
    const float* __restrict__ w_v, const float* __restrict__ w_skip,
    _Float16* __restrict__ xt16, float* __restrict__ xsum,
    _Float16* __restrict__ wfA, _Float16* __restrict__ wfT,
    _Float16* __restrict__ w_v_h, _Float16* __restrict__ wsf)
{
  const int bid = blockIdx.x;
  const int t = threadIdx.x;

  if (bid >= 768) {
    const int wb = bid - 768;         // 0..15
    for (int i = wb * 512 + t; i < wb * 512 + 512; i += 256) {
      int co = i >> 6, c = i & 63;
      float w = w_f[i];
      _Float16 hi = (_Float16)w, lo = (_Float16)(w - (float)hi);
      int laneA = (co & 15) | (((c >> 3) & 3) << 4);
      int jA = c >> 5;
      size_t oA = ((size_t)(co >> 4) * 4) * 512 + (size_t)laneA * 8 + (c & 7);
      wfA[oA + (size_t)jA * 512] = hi;
      wfA[oA + (size_t)(jA + 2) * 512] = lo;
      int laneT = (c & 15) | (((co >> 3) & 3) << 4);
      int jT = co >> 5;
      size_t oT = ((size_t)(c >> 4) * 8) * 512 + (size_t)laneT * 8 + (co & 7);
      wfT[oT + (size_t)jT * 512] = hi;
      wfT[oT + (size_t)(jT + 4) * 512] = lo;
    }
    for (int i = wb * 512 + t; i < wb * 512 + 512; i += 256)
      w_v_h[i] = (_Float16)w_v[i];
    // FULL wsf: 128*576 = 73728 elements over 16 blocks -> 4608 each
    for (int i = wb * 4608 + t; i < wb * 4608 + 4608; i += 256) {
      int co = i / 576, kk = i % 576;
      int dd = kk >> 6, c = kk & 63, dh = dd / 3, dw = dd % 3;
      int mb = co >> 4, ccol = co & 15;
      int ks = kk >> 5, g = (kk >> 3) & 3, e = kk & 7;
      size_t dst = (((size_t)mb * 18 + ks) * 64 + (ccol | (g << 4))) * 8 + e;
      wsf[dst] = (_Float16)w_skip[((co * 64 + c) * 3 + dh) * 3 + dw];
    }
    return;
  }

  const int b = bid / 48, rp = bid % 48;
  const int c = t >> 2, q = t & 3;
  __shared__ __align__(16) _Float16 xst[2 * 96 * 72];   // pitch 72 f16 = 144 B

  float pool[12];
  #pragma unroll
  for (int p = 0; p < 12; ++p) pool[p] = 0.f;

  #pragma unroll
  for (int r = 0; r < 2; ++r) {
    const float* xr = x + ((size_t)(b * 64 + c) * 96 + 2 * rp + r) * 96 + q * 24;
    #pragma unroll
    for (int j2 = 0; j2 < 6; ++j2) {
      f32x4 v = *(const f32x4*)(xr + j2 * 4);
      #pragma unroll
      for (int u = 0; u < 4; ++u) {
        int C = q * 24 + j2 * 4 + u;
        xst[(r * 96 + C) * 72 + c] = (_Float16)v[u];
        pool[(j2 * 4 + u) >> 1] += v[u];
      }
    }
  }
  {
    const int f1 = rp >= 24 ? 1 : 0, wl = rp - f1 * 24;
    #pragma unroll
    for (int p = 0; p < 12; ++p) {
      int C = q * 24 + 2 * p;
      int f2 = C >= 48 ? 1 : 0;
      int m = wl * 24 + (C - f2 * 48) / 2;
      xsum[((size_t)(b * 4 + f1 * 2 + f2) * 576 + m) * 64 + c] = 0.25f * pool[p];
    }
  }
  __syncthreads();
  for (int i = t; i < 1536; i += 256) {
    int r = i / 768, rem = i % 768, col = rem >> 3, cg = rem & 7;
    f16x8 v = *(const f16x8*)&xst[(r * 96 + col) * 72 + cg * 8];
    *(f16x8*)(xt16 + (((size_t)b * 96 + 2 * rp + r) * 96 + col) * 64 + cg * 8) = v;
  }
}

// ---------------------------------------------------------------------------
// K1b: per (m-chunk of 96, bf): centers via MFMA.
//   GEMM1: cent[co][m] = b_f[co] + sum_c wf[co][c] xc[m][c]  (3-term split)
//   norm:  ss/db reduced in-register (shfl over g) + LDS combine
//   cen = inv*cent stored hi/lo to LDS; GEMM2: cenW[m][c] = cen[m]·wf[:, c]
//   written directly in K2's fragment-major layout; dvec = inv*db.
// ---------------------------------------------------------------------------
__global__ __launch_bounds__(256) void k1b_centers(
    const float* __restrict__ xsum, const float* __restrict__ b_f,
    const _Float16* __restrict__ wfA, const _Float16* __restrict__ wfT,
    _Float16* __restrict__ cenW, float* __restrict__ dvec)
{
  const int mc = blockIdx.x;          // 0..5
  const int bf = blockIdx.y;          // 0..63
  const int m0 = mc * 96;
  const int t = threadIdx.x;
  const int lane = t & 63, wid = t >> 6;
  const int ccol = lane & 15, g = lane >> 4;

  __shared__ __align__(16) _Float16 cenT_h[96][136];
  __shared__ __align__(16) _Float16 cenT_l[96][136];
  __shared__ __align__(16) _Float16 xcs_h[96][72];
  __shared__ __align__(16) _Float16 xcs_l[96][72];
  float* part = (float*)&xcs_h[0][0];   // aliased after GEMM1 (sync-guarded)

  for (int i = t; i < 96 * 64; i += 256) {
    int m = i >> 6, c = i & 63;
    float s = xsum[((size_t)bf * 576 + m0 + m) * 64 + c];
    _Float16 hi = (_Float16)s;
    xcs_h[m][c] = hi;
    xcs_l[m][c] = (_Float16)(s - (float)hi);
  }
  __syncthreads();

  f32x4 acc[2][6];
  f32x4 bfv[2];
  #pragma unroll
  for (int cbi = 0; cbi < 2; ++cbi) {
    const int cb = wid + cbi * 4;
    bfv[cbi] = *(const f32x4*)(b_f + cb * 16 + g * 4);
    const _Float16* wa = wfA + (size_t)cb * 2048 + (size_t)lane * 8;
    f16x8 a0h = *(const f16x8*)(wa);
    f16x8 a1h = *(const f16x8*)(wa + 512);
    f16x8 a0l = *(const f16x8*)(wa + 1024);
    f16x8 a1l = *(const f16x8*)(wa + 1536);
    #pragma unroll
    for (int nb = 0; nb < 6; ++nb) {
      const int m = nb * 16 + ccol;
      f16x8 b0h = *(const f16x8*)&xcs_h[m][g * 8];
      f16x8 b1h = *(const f16x8*)&xcs_h[m][32 + g * 8];
      f16x8 b0l = *(const f16x8*)&xcs_l[m][g * 8];
      f16x8 b1l = *(const f16x8*)&xcs_l[m][32 + g * 8];
      f32x4 a2 = bfv[cbi];
      a2 = __builtin_amdgcn_mfma_f32_16x16x32_f16(a0h, b0h, a2, 0, 0, 0);
      a2 = __builtin_amdgcn_mfma_f32_16x16x32_f16(a1h, b1h, a2, 0, 0, 0);
      a2 = __builtin_amdgcn_mfma_f32_16x16x32_f16(a0h, b0l, a2, 0, 0, 0);
      a2 = __builtin_amdgcn_mfma_f32_16x16x32_f16(a1h, b1l, a2, 0, 0, 0);
      a2 = __builtin_amdgcn_mfma_f32_16x16x32_f16(a0l, b0h, a2, 0, 0, 0);
      a2 = __builtin_amdgcn_mfma_f32_16x16x32_f16(a1l, b1h, a2, 0, 0, 0);
      acc[cbi][nb] = a2;
    }
  }
  __syncthreads();   // all xcs reads complete; part may now alias it

  #pragma unroll
  for (int nb = 0; nb < 6; ++nb) {
    float ss = 0.f, db = 0.f;
    #pragma unroll
    for (int cbi = 0; cbi < 2; ++cbi)
      #pragma unroll
      for (int r = 0; r < 4; ++r) {
        float v = acc[cbi][nb][r];
        ss = fmaf(v, v, ss);
        db = fmaf(v, bfv[cbi][r], db);
      }
    #pragma unroll
    for (int off = 16; off <= 32; off <<= 1) {
      ss += __shfl_xor(ss, off, 64);
      db += __shfl_xor(db, off, 64);
    }
    if (lane < 16) {
      part[wid * 96 + nb * 16 + lane] = ss;
      part[384 + wid * 96 + nb * 16 + lane] = db;
    }
  }
  __syncthreads();
  if (t < 96) {
    float ss = part[t] + part[96 + t] + part[192 + t] + part[288 + t];
    float db = part[384 + t] + part[480 + t] + part[576 + t] + part[672 + t];
    float inv = 1.0f / fmaxf(sqrtf(ss), 1e-12f);
    part[768 + t] = inv;
    dvec[bf * 576 + m0 + t] = inv * db;
  }
  __syncthreads();

  #pragma unroll
  for (int nb = 0; nb < 6; ++nb) {
    const int m = nb * 16 + ccol;
    const float inv = part[768 + m];
    #pragma unroll
    for (int cbi = 0; cbi < 2; ++cbi) {
      const int cb = wid + cbi * 4;
      #pragma unroll
      for (int r = 0; r < 4; ++r) {
        float v = acc[cbi][nb][r] * inv;
        _Float16 hi = (_Float16)v;
        cenT_h[m][cb * 16 + g * 4 + r] = hi;
        cenT_l[m][cb * 16 + g * 4 + r] = (_Float16)(v - (float)hi);
      }
    }
  }
  __syncthreads();

  // GEMM2: wave wid owns c-block wid; B = wfT frags (global, coalesced)
  const _Float16* wt = wfT + (size_t)wid * 4096 + (size_t)lane * 8;
  f16x8 tbh[4], tbl[4];
  #pragma unroll
  for (int j2 = 0; j2 < 4; ++j2) {
    tbh[j2] = *(const f16x8*)(wt + j2 * 512);
    tbl[j2] = *(const f16x8*)(wt + (j2 + 4) * 512);
  }
  #pragma unroll 1
  for (int mb = 0; mb < 6; ++mb) {
    f16x8 tah[4], tal[4];
    #pragma unroll
    for (int j2 = 0; j2 < 4; ++j2) {
      tah[j2] = *(const f16x8*)&cenT_h[mb * 16 + ccol][j2 * 32 + g * 8];
      tal[j2] = *(const f16x8*)&cenT_l[mb * 16 + ccol][j2 * 32 + g * 8];
    }
    f32x4 a2 = {0.f, 0.f, 0.f, 0.f};
    #pragma unroll
    for (int j2 = 0; j2 < 4; ++j2) {
      a2 = __builtin_amdgcn_mfma_f32_16x16x32_f16(tah[j2], tbh[j2], a2, 0, 0, 0);
      a2 = __builtin_amdgcn_mfma_f32_16x16x32_f16(tah[j2], tbl[j2], a2, 0, 0, 0);
      a2 = __builtin_amdgcn_mfma_f32_16x16x32_f16(tal[j2], tbh[j2], a2, 0, 0, 0);
    }
    const int c = wid * 16 + ccol;
    const int lane2g = ((c >> 3) & 3) << 4;
    const int j2f = c >> 5, e = c & 7;
    #pragma unroll
    for (int r = 0; r < 4; ++r) {
      float v = a2[r];
      _Float16 hi = (_Float16)v;
      _Float16 lo = (_Float16)(v - (float)hi);
      size_t base = (((size_t)bf * 36 + mc * 6 + mb) * 4) * 512
                  + (size_t)((g * 4 + r) | lane2g) * 8 + e;
      cenW[base + (size_t)j2f * 512] = hi;
      cenW[base + (size_t)(j2f + 2) * 512] = lo;
    }
  }
}

// ---------------------------------------------------------------------------
// K2: per (bf, tile of 128 points): argmax via 3-term split f16 MFMA with
//   register-resident B, fragment-major A stream (1-deep ping-pong), dvec
//   staged in LDS; segment-sum by ownership gather into xsum
//   (pre-initialized with avgpool). XCD-affinity swizzle.
// ---------------------------------------------------------------------------
__global__ __launch_bounds__(256, 4) void k2_assign(
    const float* __restrict__ x,
    const _Float16* __restrict__ cenW,
    const float* __restrict__ dvec,
    float* __restrict__ xsum, float* __restrict__ counts)
{
  const int id = blockIdx.x;          // 0..1151
  const int xcd = id & 7;
  const int j = id >> 3;              // 0..143
  const int bf = xcd * 8 + j / 18;
  const int tile = j % 18;
  const int b = bf >> 2, f1 = (bf >> 1) & 1, f2 = bf & 1;
  const int t = threadIdx.x;
  const int lane = t & 63, wid = t >> 6;

  const int tr = tile / 3, tc = tile % 3;
  const int w0 = tr * 8, h0 = tc * 16;

  __shared__ float xs[128][65];
  __shared__ __align__(16) float dvl[576];
  __shared__ float wbv[4][64];
  __shared__ int   wbi[4][64];
  __shared__ int   idxf[128];
  __shared__ int   olist[128];
  __shared__ int   ocnt;

  if (t == 0) ocnt = 0;

  for (int i = t; i < 576; i += 256) dvl[i] = dvec[bf * 576 + i];
  for (int i = t; i < 64 * 128; i += 256) {
    int c = i >> 7, jj = i & 127;
    xs[jj][c] = x[((size_t)(b * 64 + c) * 96 + (f1 * 48 + w0 + (jj >> 4))) * 96
                  + f2 * 48 + h0 + (jj & 15)];
  }
  __syncthreads();

  const int ccol = lane & 15;
  const int g = lane >> 4;
  const int half = wid >> 1;          // mb half (0: 0..17, 1: 18..35)
  const int nbh = wid & 1;            // n-block half (0: n<64, 1: n>=64)

  f16x8 Bh0[4], Bh1[4], Bl0[4], Bl1[4];
  #pragma unroll
  for (int q = 0; q < 4; ++q) {
    const int p = (nbh * 4 + q) * 16 + ccol;
    f16x8 h0v, h1v, l0v, l1v;
    #pragma unroll
    for (int e = 0; e < 8; ++e) {
      float v0 = xs[p][g * 8 + e];
      _Float16 hi0 = (_Float16)v0;
      h0v[e] = hi0; l0v[e] = (_Float16)(v0 - (float)hi0);
      float v1 = xs[p][32 + g * 8 + e];
      _Float16 hi1 = (_Float16)v1;
      h1v[e] = hi1; l1v[e] = (_Float16)(v1 - (float)hi1);
    }
    Bh0[q] = h0v; Bh1[q] = h1v; Bl0[q] = l0v; Bl1[q] = l1v;
  }

  const int mb0 = half * 18;
  const _Float16* abase = cenW + (size_t)bf * 73728 + (size_t)mb0 * 2048
                        + (size_t)lane * 8;

  float bv[4];
  int bi[4];
  #pragma unroll
  for (int q = 0; q < 4; ++q) { bv[q] = -3.0e38f; bi[q] = 0; }

  f16x8 aA0 = *(const f16x8*)(abase);
  f16x8 aA1 = *(const f16x8*)(abase + 512);
  f16x8 aA2 = *(const f16x8*)(abase + 1024);
  f16x8 aA3 = *(const f16x8*)(abase + 1536);
  f16x8 aB0, aB1, aB2, aB3;

#define K2_BODY(kk, A0, A1, A2, A3)                                          \
  {                                                                          \
    const int mb = mb0 + (kk);                                               \
    f32x4 dv4 = *(const f32x4*)&dvl[mb * 16 + g * 4];                        \
    _Pragma("unroll")                                                        \
    for (int q = 0; q < 4; ++q) {                                            \
      f32x4 p4 = dv4;                                                        \
      f32x4 q4 = {0.f, 0.f, 0.f, 0.f};                                       \
      p4 = __builtin_amdgcn_mfma_f32_16x16x32_f16(A0, Bh0[q], p4, 0, 0, 0);  \
      q4 = __builtin_amdgcn_mfma_f32_16x16x32_f16(A1, Bh1[q], q4, 0, 0, 0);  \
      p4 = __builtin_amdgcn_mfma_f32_16x16x32_f16(A0, Bl0[q], p4, 0, 0, 0);  \
      q4 = __builtin_amdgcn_mfma_f32_16x16x32_f16(A1, Bl1[q], q4, 0, 0, 0);  \
      p4 = __builtin_amdgcn_mfma_f32_16x16x32_f16(A2, Bh0[q], p4, 0, 0, 0);  \
      q4 = __builtin_amdgcn_mfma_f32_16x16x32_f16(A3, Bh1[q], q4, 0, 0, 0);  \
      f32x4 v4 = p4 + q4;                                                    \
      _Pragma("unroll")                                                      \
      for (int r = 0; r < 4; ++r) {                                          \
        int m = mb * 16 + g * 4 + r;                                         \
        float vv = v4[r];                                                    \
        if (vv > bv[q] || (vv == bv[q] && m < bi[q])) { bv[q] = vv; bi[q] = m; } \
      }                                                                      \
    }                                                                        \
  }

  #pragma unroll 1
  for (int k = 0; k < 18; k += 2) {
    const _Float16* nb1 = abase + (size_t)(k + 1) * 2048;
    aB0 = *(const f16x8*)(nb1);
    aB1 = *(const f16x8*)(nb1 + 512);
    aB2 = *(const f16x8*)(nb1 + 1024);
    aB3 = *(const f16x8*)(nb1 + 1536);
    K2_BODY(k, aA0, aA1, aA2, aA3);
    const int kn = (k + 2 < 18) ? (k + 2) : 0;
    const _Float16* nb2 = abase + (size_t)kn * 2048;
    aA0 = *(const f16x8*)(nb2);
    aA1 = *(const f16x8*)(nb2 + 512);
    aA2 = *(const f16x8*)(nb2 + 1024);
    aA3 = *(const f16x8*)(nb2 + 1536);
    K2_BODY(k + 1, aB0, aB1, aB2, aB3);
  }
#undef K2_BODY

  #pragma unroll
  for (int q = 0; q < 4; ++q) {
    float v = bv[q]; int mi = bi[q];
    #pragma unroll
    for (int off = 16; off <= 32; off <<= 1) {
      float ov = __shfl_xor(v, off, 64);
      int   oi = __shfl_xor(mi, off, 64);
      if (ov > v || (ov == v && oi < mi)) { v = ov; mi = oi; }
    }
    if (lane < 16) { wbv[wid][q * 16 + lane] = v; wbi[wid][q * 16 + lane] = mi; }
  }
  __syncthreads();

  if (t < 128) {
    int nbg = t >> 6;
    int s = t & 63;
    float v0 = wbv[nbg][s];     int i0 = wbi[nbg][s];
    float v1 = wbv[nbg + 2][s]; int i1 = wbi[nbg + 2][s];
    int mi = (v1 > v0 || (v1 == v0 && i1 < i0)) ? i1 : i0;
    idxf[t] = mi;
    int own = (tr * 4 + ((t >> 4) >> 1)) * 24 + tc * 8 + ((t & 15) >> 1);
    if (mi != own) { int o = atomicAdd(&ocnt, 1); olist[o] = t; }
  }
  __syncthreads();

  for (int si = 0; si < 8; ++si) {
    const int s = wid * 8 + si;
    const int r = s >> 3, q = s & 7;
    const int m = (tr * 4 + r) * 24 + tc * 8 + q;
    const int p00 = (2 * r) * 16 + 2 * q;
    float sum = 0.f;
    int cnt = 0;
    #pragma unroll
    for (int dp = 0; dp < 4; ++dp) {
      const int p = p00 + (dp >> 1) * 16 + (dp & 1);
      if (idxf[p] == m) { sum += xs[p][lane]; ++cnt; }
    }
    if (cnt > 0) {
      atomicAdd(&xsum[((size_t)bf * 576 + m) * 64 + lane], sum);
      if (lane == 0) atomicAdd(&counts[bf * 576 + m], (float)cnt);
    }
  }

  for (int o = wid; o < ocnt; o += 4) {
    const int p = olist[o];
    const int m = idxf[p];
    atomicAdd(&xsum[((size_t)bf * 576 + m) * 64 + lane], xs[p][lane]);
    if (lane == 0) atomicAdd(&counts[bf * 576 + m], 1.0f);
  }
}

// ---------------------------------------------------------------------------
// K2c: pooled GEMM + divide + GroupNorm stats:
//   om[m][co] = (W_v·xsum[m])/(cnt[m]+1) + b_v[co]   (f16 out)
// ---------------------------------------------------------------------------
__global__ __launch_bounds__(256) void k2c_pool(
    const float* __restrict__ xsum,
    const float* __restrict__ counts, const _Float16* __restrict__ w_v_h,
    const float* __restrict__ b_v, _Float16* __restrict__ om,
    float* __restrict__ gn_sum, float* __restrict__ gn_ss)
{
  const int chunk = blockIdx.x;       // 0..3
  const int bf = blockIdx.y;          // 0..63
  const int m0 = chunk * 144;
  const int t = threadIdx.x;
  const int lane = t & 63, wid = t >> 6;

  __shared__ __align__(16) _Float16 bh[144][72];
  __shared__ __align__(16) _Float16 bl[144][72];
  __shared__ float rcp_l[144];

  for (int i = t; i < 144 * 64; i += 256) {
    int mq = i >> 6, c = i & 63;
    size_t gdx = ((size_t)bf * 576 + m0 + mq) * 64 + c;
    float s = xsum[gdx];
    _Float16 hi = (_Float16)s;
    bh[mq][c] = hi;
    bl[mq][c] = (_Float16)(s - (float)hi);
  }
  if (t < 144) rcp_l[t] = 1.0f / (counts[bf * 576 + m0 + t] + 1.0f);
  __syncthreads();

  const int ccol = lane & 15, row0 = (lane >> 4) * 4, c0 = (lane >> 4) * 8;
  float sacc = 0.f, ssacc = 0.f;

  #pragma unroll
  for (int cbi = 0; cbi < 2; ++cbi) {
    const int cb = wid + cbi * 4;
    const size_t abase = (size_t)(cb * 16 + ccol) * 64;
    f16x8 a0 = *(const f16x8*)(w_v_h + abase + c0);
    f16x8 a1 = *(const f16x8*)(w_v_h + abase + 32 + c0);
    float bvv[4];
    #pragma unroll
    for (int r = 0; r < 4; ++r) bvv[r] = b_v[cb * 16 + row0 + r];
    for (int nb = 0; nb < 9; ++nb) {
      int mq = nb * 16 + ccol;
      f16x8 bh0 = *(const f16x8*)(&bh[mq][c0]);
      f16x8 bh1 = *(const f16x8*)(&bh[mq][32 + c0]);
      f16x8 bl0 = *(const f16x8*)(&bl[mq][c0]);
      f16x8 bl1 = *(const f16x8*)(&bl[mq][32 + c0]);
      f32x4 a2 = {0.f, 0.f, 0.f, 0.f};
      a2 = __builtin_amdgcn_mfma_f32_16x16x32_f16(a0, bh0, a2, 0, 0, 0);
      a2 = __builtin_amdgcn_mfma_f32_16x16x32_f16(a1, bh1, a2, 0, 0, 0);
      a2 = __builtin_amdgcn_mfma_f32_16x16x32_f16(a0, bl0, a2, 0, 0, 0);
      a2 = __builtin_amdgcn_mfma_f32_16x16x32_f16(a1, bl1, a2, 0, 0, 0);
      float rcp = rcp_l[mq];
      f16x4 o4;
      #pragma unroll
      for (int r = 0; r < 4; ++r) {
        float ov = a2[r] * rcp + bvv[r];
        sacc += ov; ssacc += ov * ov;
        o4[r] = (_Float16)ov;
      }
      *(f16x4*)(om + ((size_t)bf * 576 + m0 + mq) * 128 + cb * 16 + row0) = o4;
    }
  }

  #pragma unroll
  for (int off = 1; off < 64; off <<= 1) {
    sacc += __shfl_xor(sacc, off, 64);
    ssacc += __shfl_xor(ssacc, off, 64);
  }
  __shared__ float rs[4], rss[4];
  if (lane == 0) { rs[wid] = sacc; rss[wid] = ssacc; }
  __syncthreads();
  if (t == 0) {
    atomicAdd(gn_sum + (bf >> 2), rs[0] + rs[1] + rs[2] + rs[3]);
    atomicAdd(gn_ss + (bf >> 2), rss[0] + rss[1] + rss[2] + rss[3]);
  }
}

// ---------------------------------------------------------------------------
// K4: per (b, output row o2): skip conv as implicit GEMM, A from
//   fragment-major wsf, B from xt16 staged in LDS with XOR chunk-swizzle;
//   epilogue: GroupNorm apply + unfold + bias + add.
// ---------------------------------------------------------------------------
__global__ __launch_bounds__(256, 4) void k4_final(
    const _Float16* __restrict__ xt16, const _Float16* __restrict__ wsf,
    const float* __restrict__ b_skip, const _Float16* __restrict__ om,
    const float* __restrict__ gn_sum, const float* __restrict__ gn_ss,
    const float* __restrict__ gamma, const float* __restrict__ beta,
    float* __restrict__ out)
{
  const int o2 = blockIdx.x;          // 0..47
  const int b  = blockIdx.y;          // 0..15
  const int t = threadIdx.x;
  const int lane = t & 63, wid = t >> 6;

  __shared__ __align__(16) _Float16 xl[3 * 97 * 64];

  if (t < 96) {
    int rr = t >> 5, h2 = t & 31;
    *(unsigned int*)&xl[(rr * 97) * 64 + h2 * 2] = 0u;
  }
  for (int i = t; i < 2304; i += 256) {
    int rr = i / 768, rem = i % 768, col = rem >> 3, cg = rem & 7;
    int gr = 2 * o2 - 1 + rr;
    f16x8 v = {};
    if (gr >= 0)
      v = *(const f16x8*)(xt16 + (((size_t)b * 96 + gr) * 96 + col) * 64 + cg * 8);
    int colp = col + 1;
    *(f16x8*)&xl[(rr * 97 + colp) * 64 + ((cg ^ (colp & 7)) << 3)] = v;
  }
  __syncthreads();

  const int ccol = lane & 15, g = lane >> 4;
  const int mb0 = wid * 2;

  f32x4 acc[2][3] = {};
  const int o3a = ccol;

  #pragma unroll 1
  for (int kc = 0; kc < 6; ++kc) {
    f16x8 A[2][3];
    #pragma unroll
    for (int m2 = 0; m2 < 2; ++m2)
      #pragma unroll
      for (int kq = 0; kq < 3; ++kq) {
        int ks = kc * 3 + kq;
        A[m2][kq] = *(const f16x8*)(wsf + (((size_t)(mb0 + m2) * 18 + ks) * 64 + lane) * 8);
      }
    #pragma unroll
    for (int nb = 0; nb < 3; ++nb) {
      const int o3 = nb * 16 + o3a;
      f16x8 Bf[3];
      #pragma unroll
      for (int kq = 0; kq < 3; ++kq) {
        int ks = kc * 3 + kq;
        int dd = ks >> 1, dh = dd / 3, dw = dd % 3, ch = ks & 1;
        int colp = 2 * o3 + dw;
        Bf[kq] = *(const f16x8*)&xl[(dh * 97 + colp) * 64
                                    + ((((ch << 2) | g) ^ (colp & 7)) << 3)];
      }
      #pragma unroll
      for (int kq = 0; kq < 3; ++kq) {
        acc[0][nb] = __builtin_amdgcn_mfma_f32_16x16x32_f16(A[0][kq], Bf[kq], acc[0][nb], 0, 0, 0);
        acc[1][nb] = __builtin_amdgcn_mfma_f32_16x16x32_f16(A[1][kq], Bf[kq], acc[1][nb], 0, 0, 0);
      }
    }
  }

  const float Ninv = 1.0f / 294912.0f;
  const float mu = gn_sum[b] * Ninv;
  const float var = gn_ss[b] * Ninv - mu * mu;
  const float istd = rsqrtf(var + 1e-5f);
  const int f1 = o2 / 24, w24 = o2 % 24;

  #pragma unroll
  for (int m2 = 0; m2 < 2; ++m2) {
    const int mb = mb0 + m2;
    #pragma unroll
    for (int nb = 0; nb < 3; ++nb) {
      const int o3 = nb * 16 + o3a;
      const int f2 = o3 / 24, h = o3 % 24;
      const int bf = b * 4 + f1 * 2 + f2;
      const int m = w24 * 24 + h;
      f16x4 o4 = *(const f16x4*)(om + ((size_t)bf * 576 + m) * 128 + mb * 16 + g * 4);
      #pragma unroll
      for (int r = 0; r < 4; ++r) {
        int co = mb * 16 + g * 4 + r;
        float gnv = ((float)o4[r] - mu) * istd * gamma[co] + beta[co];
        out[((size_t)(b * 128 + co) * 48 + o2) * 48 + o3] = acc[m2][nb][r] + b_skip[co] + gnv;
      }
    }
  }
}

// ---------------------------------------------------------------------------
extern "C" void kernel_launch(void* const* d_in, const int* in_sizes, int n_in,
                              void* d_out, int out_size, void* d_ws, size_t ws_size,
                              hipStream_t stream) {
  const float* x      = (const float*)d_in[0];
  const float* w_f    = (const float*)d_in[1];
  const float* b_f    = (const float*)d_in[2];
  const float* w_v    = (const float*)d_in[3];
  const float* b_v    = (const float*)d_in[4];
  const float* w_skip = (const float*)d_in[5];
  const float* b_skip = (const float*)d_in[6];
  const float* gamma  = (const float*)d_in[7];
  const float* beta   = (const float*)d_in[8];
  float* out = (float*)d_out;

  char* ws = (char*)d_ws;
  _Float16* cenW   = (_Float16*)(ws);                 // 9,437,184 (frag-major hi+lo)
  _Float16* om     = (_Float16*)(ws);                 // aliases cenW (dead after K2)
  float*    dvec   = (float*)(ws + 9437184);          // 147,456
  _Float16* wsf    = (_Float16*)(ws + 9584640);       // 147,456
  _Float16* w_v_h  = (_Float16*)(ws + 9732096);       // 16,384
  float*    xsum   = (float*)(ws + 9748480);          // 9,437,184 (init by K1a)
  float*    counts = (float*)(ws + 19185664);         // 147,456   [memset]
  float*    gn_sum = (float*)(ws + 19333120);         // 256       [memset]
  float*    gn_ss  = (float*)(ws + 19333376);         // 256       [memset]
  _Float16* xt16   = (_Float16*)(ws + 19333632);      // 18,874,368
  _Float16* wfA    = (_Float16*)(ws + 38208000);      // 32,768
  _Float16* wfT    = (_Float16*)(ws + 38240768);      // 32,768  (end 38,273,536)

  hipMemsetAsync(ws + 19185664, 0, 147968, stream);

  k1a_prep<<<dim3(784), dim3(256), 0, stream>>>(
      x, w_f, w_v, w_skip, xt16, xsum, wfA, wfT, w_v_h, wsf);
  k1b_centers<<<dim3(6, 64), dim3(256), 0, stream>>>(
      xsum, b_f, wfA, wfT, cenW, dvec);
  k2_assign<<<dim3(1152), dim3(256), 0, stream>>>(
      x, cenW, dvec, xsum, counts);
  k2c_pool<<<dim3(4, 64), dim3(256), 0, stream>>>(
      xsum, counts, w_v_h, b_v, om, gn_sum, gn_ss);
  k4_final<<<dim3(48, 16), dim3(256), 0, stream>>>(
      xt16, wsf, b_skip, om, gn_sum, gn_ss, gamma, beta, out);
}